// Round 2
// baseline (1322.066 us; speedup 1.0000x reference)
//
#include <hip/hip_runtime.h>

#define N_NODES 50000
#define DIM     256
#define R_REL   4
#define E_EDGES 500000
#define NV_VUL  10000
#define K_CAND  8
#define EPS_C   1e-8f
#define RN      (R_REL * N_NODES)            // 200000
#define SCAN_B  1024
#define SCAN_G  ((RN + SCAN_B - 1) / SCAN_B) // 196

// ---------------- GEMM: C[M x 256] = A[M x 256] * B[256 x 256] (+bias) ----
#define BM 64
#define BN 64
#define BK 64
__global__ __launch_bounds__(256) void k_gemm(const float* __restrict__ A,
                                              const float* __restrict__ B,
                                              const float* __restrict__ bias,
                                              float* __restrict__ C, int M) {
  __shared__ float As[BK][BM + 1];
  __shared__ float Bs[BK][BN];
  const int t   = threadIdx.x;
  const int bn0 = blockIdx.x * BN;
  const int bm0 = blockIdx.y * BM;
  const int lr  = t >> 4;   // 0..15
  const int lq  = t & 15;   // 0..15
  const int tm  = t >> 4;
  const int tn  = t & 15;
  float acc[4][4] = {};
  for (int k0 = 0; k0 < DIM; k0 += BK) {
#pragma unroll
    for (int i = 0; i < 4; i++) {
      int row = lr + i * 16;
      int gm  = bm0 + row; if (gm >= M) gm = M - 1;   // clamp (stores guarded)
      const float4 a4 = *(const float4*)(A + (size_t)gm * DIM + k0 + lq * 4);
      As[lq * 4 + 0][row] = a4.x;
      As[lq * 4 + 1][row] = a4.y;
      As[lq * 4 + 2][row] = a4.z;
      As[lq * 4 + 3][row] = a4.w;
      int kr = lr + i * 16;
      const float4 b4 = *(const float4*)(B + (size_t)(k0 + kr) * DIM + bn0 + lq * 4);
      *(float4*)&Bs[kr][lq * 4] = b4;
    }
    __syncthreads();
#pragma unroll
    for (int kk = 0; kk < BK; kk++) {
      float a0 = As[kk][tm * 4 + 0];
      float a1 = As[kk][tm * 4 + 1];
      float a2 = As[kk][tm * 4 + 2];
      float a3 = As[kk][tm * 4 + 3];
      const float4 b4 = *(const float4*)&Bs[kk][tn * 4];
      acc[0][0] += a0 * b4.x; acc[0][1] += a0 * b4.y; acc[0][2] += a0 * b4.z; acc[0][3] += a0 * b4.w;
      acc[1][0] += a1 * b4.x; acc[1][1] += a1 * b4.y; acc[1][2] += a1 * b4.z; acc[1][3] += a1 * b4.w;
      acc[2][0] += a2 * b4.x; acc[2][1] += a2 * b4.y; acc[2][2] += a2 * b4.z; acc[2][3] += a2 * b4.w;
      acc[3][0] += a3 * b4.x; acc[3][1] += a3 * b4.y; acc[3][2] += a3 * b4.z; acc[3][3] += a3 * b4.w;
    }
    __syncthreads();
  }
#pragma unroll
  for (int i = 0; i < 4; i++) {
    int gm = bm0 + tm * 4 + i;
    if (gm < M) {
      float4 o;
      o.x = acc[i][0]; o.y = acc[i][1]; o.z = acc[i][2]; o.w = acc[i][3];
      if (bias) {
        o.x += bias[bn0 + tn * 4 + 0];
        o.y += bias[bn0 + tn * 4 + 1];
        o.z += bias[bn0 + tn * 4 + 2];
        o.w += bias[bn0 + tn * 4 + 3];
      }
      *(float4*)(C + (size_t)gm * DIM + bn0 + tn * 4) = o;
    }
  }
}

// ---------------- per-row L2 norms (one wave per row) ----------------
__global__ __launch_bounds__(256) void k_norm(const float* __restrict__ H,
                                              float* __restrict__ nrm, int M) {
  int w    = (int)((blockIdx.x * (size_t)blockDim.x + threadIdx.x) >> 6);
  int lane = threadIdx.x & 63;
  if (w >= M) return;
  const float4 v = *(const float4*)(H + (size_t)w * DIM + lane * 4);
  float ss = v.x * v.x + v.y * v.y + v.z * v.z + v.w * v.w;
  for (int off = 32; off; off >>= 1) ss += __shfl_xor(ss, off);
  if (lane == 0) nrm[w] = sqrtf(ss);
}

// ---------------- CSR build: count / scan / scatter ----------------
__global__ void k_count(const int* __restrict__ dst, int* __restrict__ counts) {
  int e = blockIdx.x * blockDim.x + threadIdx.x;
  if (e >= R_REL * E_EDGES) return;
  int r = e / E_EDGES;
  atomicAdd(&counts[r * N_NODES + dst[e]], 1);
}

__global__ __launch_bounds__(SCAN_B) void k_bsum(const int* __restrict__ counts,
                                                 int* __restrict__ bsum) {
  __shared__ int sh[16];
  int i = blockIdx.x * SCAN_B + threadIdx.x;
  int v = (i < RN) ? counts[i] : 0;
  for (int off = 32; off; off >>= 1) v += __shfl_xor(v, off);
  int wid = threadIdx.x >> 6, lane = threadIdx.x & 63;
  if (lane == 0) sh[wid] = v;
  __syncthreads();
  if (threadIdx.x < 16) {
    int s = sh[threadIdx.x];
    for (int off = 8; off; off >>= 1) s += __shfl_xor(s, off, 16);
    if (threadIdx.x == 0) bsum[blockIdx.x] = s;
  }
}

__global__ __launch_bounds__(256) void k_scanb(const int* __restrict__ bsum,
                                               int* __restrict__ bbase,
                                               int* __restrict__ offsets) {
  __shared__ int s[256];
  int tid = threadIdx.x;
  int v = (tid < SCAN_G) ? bsum[tid] : 0;
  s[tid] = v;
  __syncthreads();
  for (int off = 1; off < 256; off <<= 1) {
    int t2 = (tid >= off) ? s[tid - off] : 0;
    __syncthreads();
    s[tid] += t2;
    __syncthreads();
  }
  if (tid < SCAN_G) bbase[tid] = s[tid] - v;
  if (tid == 255) offsets[RN] = s[255];
}

// cursor may alias counts: each i is read exactly once here before being rewritten.
__global__ __launch_bounds__(SCAN_B) void k_scanlocal(const int* __restrict__ counts_in,
                                                      const int* __restrict__ bbase,
                                                      int* __restrict__ offsets,
                                                      int* __restrict__ cursor) {
  __shared__ int s[SCAN_B];
  int tid = threadIdx.x;
  int i = blockIdx.x * SCAN_B + tid;
  int v = (i < RN) ? counts_in[i] : 0;
  s[tid] = v;
  __syncthreads();
  for (int off = 1; off < SCAN_B; off <<= 1) {
    int t2 = (tid >= off) ? s[tid - off] : 0;
    __syncthreads();
    s[tid] += t2;
    __syncthreads();
  }
  if (i < RN) {
    int excl = s[tid] - v + bbase[blockIdx.x];
    offsets[i] = excl;
    cursor[i]  = excl;
  }
}

__global__ void k_scatter(const int* __restrict__ src, const int* __restrict__ dst,
                          int* cursor, int* __restrict__ edge_src) {
  int e = blockIdx.x * blockDim.x + threadIdx.x;
  if (e >= R_REL * E_EDGES) return;
  int r = e / E_EDGES;
  int pos = atomicAdd(&cursor[r * N_NODES + dst[e]], 1);
  edge_src[pos] = src[e];
}

// ---------------- edge aggregation: one wave per (r, dst-node) ----------------
__global__ __launch_bounds__(256) void k_aggregate(int r,
                                                   const float* __restrict__ hr,
                                                   const float* __restrict__ ht,
                                                   const float* __restrict__ nrm_hr,
                                                   const float* __restrict__ nrm_ht,
                                                   const int* __restrict__ offsets,
                                                   const int* __restrict__ edge_src,
                                                   float* __restrict__ h,
                                                   float* __restrict__ ma) {
  int n    = (int)((blockIdx.x * (size_t)blockDim.x + threadIdx.x) >> 6);
  int lane = threadIdx.x & 63;
  if (n >= N_NODES) return;
  const float4 hd = *(const float4*)(ht + (size_t)n * DIM + lane * 4);
  float ndst = fmaxf(nrm_ht[n], EPS_C);
  int b     = offsets[r * N_NODES + n];
  int e_end = offsets[r * N_NODES + n + 1];
  float4 acc = {0.f, 0.f, 0.f, 0.f};
  float asum = 0.f;
  for (int e = b; e < e_end; e++) {
    int sn = edge_src[e];
    const float4 hs = *(const float4*)(hr + (size_t)sn * DIM + lane * 4);
    float num = hs.x * hd.x + hs.y * hd.y + hs.z * hd.z + hs.w * hd.w;
    for (int off = 32; off; off >>= 1) num += __shfl_xor(num, off);
    float s = num / (fmaxf(nrm_hr[sn], EPS_C) * ndst);
    acc.x += s * hs.x; acc.y += s * hs.y; acc.z += s * hs.z; acc.w += s * hs.w;
    asum += s;
  }
  *(float4*)(h + ((size_t)n * R_REL + r) * DIM + lane * 4) = acc;
  if (lane == 0) {
    float cnt = (float)(e_end - b);
    ma[n * R_REL + r] = asum / fmaxf(cnt, 1.0f);
  }
}

// ------- vulnerable nodes: distance-softmax mask + combine, writes out directly ----
__global__ __launch_bounds__(1024) void k_vuln_combine(const float* __restrict__ h,
                                                       const int* __restrict__ cand,
                                                       const float* __restrict__ ma,
                                                       float* __restrict__ out) {
  __shared__ float red[8][16];
  __shared__ float dist2[8];
  __shared__ float sm[4][256];
  int n   = blockIdx.x;
  int tid = threadIdx.x;                       // (r,d): r = tid>>8, d = tid&255
  float hv = h[(size_t)n * 1024 + tid];
  float d2k[8];
#pragma unroll
  for (int k = 0; k < 8; k++) {
    int c = cand[n * 8 + k];
    float hc = h[(size_t)c * 1024 + tid];
    float df = hv - hc;
    d2k[k] = df * df;
  }
  int wid = tid >> 6, lane = tid & 63;
#pragma unroll
  for (int k = 0; k < 8; k++) {
    float v = d2k[k];
    for (int off = 32; off; off >>= 1) v += __shfl_xor(v, off);
    if (lane == 0) red[k][wid] = v;
  }
  __syncthreads();
  if (tid < 128) {
    int k = tid >> 4, w2 = tid & 15;
    float v = red[k][w2];
    for (int off = 8; off; off >>= 1) v += __shfl_xor(v, off, 16);
    if (w2 == 0) dist2[k] = v;
  }
  __syncthreads();
  float dk[8], mn = 1e30f;
#pragma unroll
  for (int k = 0; k < 8; k++) { dk[k] = sqrtf(dist2[k]); mn = fminf(mn, dk[k]); }
  float se = 0.f, att[8];
#pragma unroll
  for (int k = 0; k < 8; k++) { att[k] = expf(mn - dk[k]); se += att[k]; }
  float inv = 1.f / se;
  float acc = 0.f;
#pragma unroll
  for (int k = 0; k < 8; k++) acc += att[k] * inv * d2k[k];
  float masked = hv * expf(-acc);
  // combine weights: softmax over ma[n, 0..3]
  float m0 = ma[n * 4 + 0], m1 = ma[n * 4 + 1], m2 = ma[n * 4 + 2], m3 = ma[n * 4 + 3];
  float mx = fmaxf(fmaxf(m0, m1), fmaxf(m2, m3));
  float w0 = expf(m0 - mx), w1 = expf(m1 - mx), w2f = expf(m2 - mx), w3 = expf(m3 - mx);
  float winv = 1.f / (w0 + w1 + w2f + w3);
  float wr = (tid < 256) ? w0 : (tid < 512) ? w1 : (tid < 768) ? w2f : w3;
  sm[tid >> 8][tid & 255] = wr * winv * masked;
  __syncthreads();
  if (tid < 256)
    out[(size_t)n * 256 + tid] = sm[0][tid] + sm[1][tid] + sm[2][tid] + sm[3][tid];
}

// ---------------- combine for non-vulnerable nodes ----------------
__global__ __launch_bounds__(256) void k_combine_rest(const float* __restrict__ h,
                                                      const float* __restrict__ ma,
                                                      float* __restrict__ out) {
  int n = NV_VUL + blockIdx.x;
  int d = threadIdx.x;
  float m0 = ma[n * 4 + 0], m1 = ma[n * 4 + 1], m2 = ma[n * 4 + 2], m3 = ma[n * 4 + 3];
  float mx = fmaxf(fmaxf(m0, m1), fmaxf(m2, m3));
  float w0 = expf(m0 - mx), w1 = expf(m1 - mx), w2 = expf(m2 - mx), w3 = expf(m3 - mx);
  float inv = 1.f / (w0 + w1 + w2 + w3);
  const float* hs = h + (size_t)n * 1024;
  float v = w0 * hs[d] + w1 * hs[256 + d] + w2 * hs[512 + d] + w3 * hs[768 + d];
  out[(size_t)n * 256 + d] = v * inv;
}

// ---------------- diagnostic fallback: encode ws_size(MB) into out[0] ----------
__global__ void k_fallback(float* __restrict__ out, int out_size, float wsmb) {
  int i = blockIdx.x * blockDim.x + threadIdx.x;
  if (i < out_size) out[i] = (i == 0) ? wsmb : 0.f;
}

extern "C" void kernel_launch(void* const* d_in, const int* in_sizes, int n_in,
                              void* d_out, int out_size, void* d_ws, size_t ws_size,
                              hipStream_t stream) {
  const float* x   = (const float*)d_in[0];
  const float* We  = (const float*)d_in[1];
  const float* Wn  = (const float*)d_in[2];
  const float* bnb = (const float*)d_in[3];
  const int* src   = (const int*)d_in[4];
  const int* dst   = (const int*)d_in[5];
  const int* cand  = (const int*)d_in[6];
  float* out = (float*)d_out;

  char* ws = (char*)d_ws;
  size_t off = 0;
  auto alloc = [&](size_t bytes) -> void* {
    void* p = ws + off;
    off += (bytes + 255) & ~(size_t)255;
    return p;
  };
  float* ht     = (float*)alloc((size_t)N_NODES * DIM * 4);            // 51.2 MB
  float* h      = (float*)alloc((size_t)N_NODES * R_REL * DIM * 4);    // 204.8 MB
  float* ma     = (float*)alloc((size_t)N_NODES * R_REL * 4);
  float* nrm_ht = (float*)alloc((size_t)N_NODES * 4);
  float* nrm_hr = (float*)alloc((size_t)N_NODES * 4);
  int* counts   = (int*)alloc((size_t)RN * 4);                         // aliased as cursor
  int* offsets  = (int*)alloc((size_t)(RN + 1) * 4);
  int* bsum     = (int*)alloc((size_t)SCAN_G * 4);
  int* bbase    = (int*)alloc((size_t)SCAN_G * 4);
  int* edge_src = (int*)alloc((size_t)R_REL * E_EDGES * 4);            // 8 MB
  size_t required = off;
  (void)in_sizes; (void)n_in;

  if (ws_size < required) {
    // diagnostic: absmax will approximate ws_size in MB
    k_fallback<<<(out_size + 255) / 256, 256, 0, stream>>>(out, out_size,
                                                           (float)(ws_size >> 20));
    return;
  }

  float* hr = out;               // d_out doubles as the per-relation projection buffer
  int* cursor = counts;          // safe alias (see k_scanlocal)

  hipMemsetAsync(counts, 0, (size_t)RN * 4, stream);

  dim3 gemm_grid(DIM / BN, (N_NODES + BM - 1) / BM);

  // ht = x @ Wn + bn, and its row norms
  k_gemm<<<gemm_grid, 256, 0, stream>>>(x, Wn, bnb, ht, N_NODES);
  k_norm<<<(N_NODES * 64 + 255) / 256, 256, 0, stream>>>(ht, nrm_ht, N_NODES);

  // CSR by (r, dst)
  k_count<<<(R_REL * E_EDGES + 255) / 256, 256, 0, stream>>>(dst, counts);
  k_bsum<<<SCAN_G, SCAN_B, 0, stream>>>(counts, bsum);
  k_scanb<<<1, 256, 0, stream>>>(bsum, bbase, offsets);
  k_scanlocal<<<SCAN_G, SCAN_B, 0, stream>>>(counts, bbase, offsets, cursor);
  k_scatter<<<(R_REL * E_EDGES + 255) / 256, 256, 0, stream>>>(src, dst, cursor, edge_src);

  // per relation: hr = x @ We[r]; aggregate into h[:, r, :], ma[:, r]
  for (int r = 0; r < R_REL; r++) {
    k_gemm<<<gemm_grid, 256, 0, stream>>>(x, We + (size_t)r * DIM * DIM, nullptr, hr, N_NODES);
    k_norm<<<(N_NODES * 64 + 255) / 256, 256, 0, stream>>>(hr, nrm_hr, N_NODES);
    k_aggregate<<<(N_NODES * 64 + 255) / 256, 256, 0, stream>>>(
        r, hr, ht, nrm_hr, nrm_ht, offsets, edge_src, h, ma);
  }

  // vulnerable nodes: mask + combine (reads pristine h, writes out rows [0, NV))
  k_vuln_combine<<<NV_VUL, 1024, 0, stream>>>(h, cand, ma, out);

  // non-vulnerable nodes: combine (writes out rows [NV, N))
  k_combine_rest<<<N_NODES - NV_VUL, 256, 0, stream>>>(h, ma, out);
}

// Round 3
// 1039.156 us; speedup vs baseline: 1.2723x; 1.2723x over previous
//
#include <hip/hip_runtime.h>

#define N_NODES 50000
#define DIM     256
#define R_REL   4
#define E_EDGES 500000
#define NV_VUL  10000
#define K_CAND  8
#define EPS_C   1e-8f
#define RN      (R_REL * N_NODES)            // 200000
#define SCAN_B  1024
#define SCAN_G  ((RN + SCAN_B - 1) / SCAN_B) // 196

typedef short bf16x8 __attribute__((ext_vector_type(8)));
typedef float f32x4  __attribute__((ext_vector_type(4)));

__device__ __forceinline__ unsigned short f2bf_rne(float f) {
  unsigned u = __builtin_bit_cast(unsigned, f);
  unsigned r = (u + 0x7FFFu + ((u >> 16) & 1u)) >> 16;
  return (unsigned short)r;
}
__device__ __forceinline__ float bf2f(unsigned short h) {
  unsigned u = ((unsigned)h) << 16;
  return __builtin_bit_cast(float, u);
}
// 8 floats -> bf16 hi + bf16 lo (residual)
__device__ __forceinline__ void cvt8(float4 a, float4 b, bf16x8* h, bf16x8* l) {
  float f[8] = {a.x, a.y, a.z, a.w, b.x, b.y, b.z, b.w};
  bf16x8 hh, ll;
#pragma unroll
  for (int i = 0; i < 8; i++) {
    unsigned short hv = f2bf_rne(f[i]);
    hh[i] = (short)hv;
    ll[i] = (short)f2bf_rne(f[i] - bf2f(hv));
  }
  *h = hh; *l = ll;
}

// ---- weight prep: Bt_hi[w][n][k], Bt_lo[w][n][k] = split(W_w[k][n]) ----
__global__ __launch_bounds__(256) void k_convert_w(const float* __restrict__ Wn,
                                                   const float* __restrict__ We,
                                                   short* __restrict__ Bthi,
                                                   short* __restrict__ Btlo) {
  __shared__ float tile[64][65];
  int w  = blockIdx.z;                    // 0 = Wn, 1..4 = We[w-1]
  int k0 = blockIdx.x * 64, n0 = blockIdx.y * 64;
  const float* W = (w == 0) ? Wn : We + (size_t)(w - 1) * 65536;
  int tx = threadIdx.x & 63, ty = threadIdx.x >> 6;
  for (int i = ty; i < 64; i += 4)
    tile[i][tx] = W[(size_t)(k0 + i) * 256 + n0 + tx];
  __syncthreads();
  for (int i = ty; i < 64; i += 4) {
    float f = tile[tx][i];                // = W[k0+tx][n0+i]
    unsigned short h = f2bf_rne(f);
    size_t o = (size_t)w * 65536 + (size_t)(n0 + i) * 256 + k0 + tx;
    Bthi[o] = (short)h;
    Btlo[o] = (short)f2bf_rne(f - bf2f(h));
  }
}

// ---- split-bf16 MFMA GEMM: C[M x 256] = A[M x 256] @ W (+bias), fused row sumsq ----
#define GBM 128
#define GBN 128
#define GBK 32
__global__ __launch_bounds__(256) void k_gemm_mfma(const float* __restrict__ A,
                                                   const short* __restrict__ Bthi,
                                                   const short* __restrict__ Btlo,
                                                   const float* __restrict__ bias,
                                                   float* __restrict__ C,
                                                   float* __restrict__ nrm_sq,
                                                   int M) {
  __shared__ short Ahi_s[128][GBK + 8];
  __shared__ short Alo_s[128][GBK + 8];
  __shared__ short Bhi_s[128][GBK + 8];
  __shared__ short Blo_s[128][GBK + 8];
  const int t    = threadIdx.x;
  const int bm0  = blockIdx.x * GBM;
  const int bn0  = blockIdx.y * GBN;
  const int wave = t >> 6, lane = t & 63;
  const int wm   = (wave >> 1) * 64, wn = (wave & 1) * 64;
  const int m16  = lane & 15, kg = lane >> 4;

  f32x4 acc[4][4] = {};

  const int srow  = t >> 1;
  const int shalf = t & 1;                // 16-element half of the 32-wide K tile
  int agrow = bm0 + srow; if (agrow >= M) agrow = M - 1;
  const float* aptr   = A    + (size_t)agrow * 256 + shalf * 16;
  const short* bhiptr = Bthi + (size_t)(bn0 + srow) * 256 + shalf * 16;
  const short* bloptr = Btlo + (size_t)(bn0 + srow) * 256 + shalf * 16;

  for (int k0 = 0; k0 < DIM; k0 += GBK) {
    float4 av0 = *(const float4*)(aptr + k0);
    float4 av1 = *(const float4*)(aptr + k0 + 4);
    float4 av2 = *(const float4*)(aptr + k0 + 8);
    float4 av3 = *(const float4*)(aptr + k0 + 12);
    bf16x8 h0, l0, h1, l1;
    cvt8(av0, av1, &h0, &l0);
    cvt8(av2, av3, &h1, &l1);
    *(bf16x8*)&Ahi_s[srow][shalf * 16 + 0] = h0;
    *(bf16x8*)&Ahi_s[srow][shalf * 16 + 8] = h1;
    *(bf16x8*)&Alo_s[srow][shalf * 16 + 0] = l0;
    *(bf16x8*)&Alo_s[srow][shalf * 16 + 8] = l1;
    *(bf16x8*)&Bhi_s[srow][shalf * 16 + 0] = *(const bf16x8*)(bhiptr + k0);
    *(bf16x8*)&Bhi_s[srow][shalf * 16 + 8] = *(const bf16x8*)(bhiptr + k0 + 8);
    *(bf16x8*)&Blo_s[srow][shalf * 16 + 0] = *(const bf16x8*)(bloptr + k0);
    *(bf16x8*)&Blo_s[srow][shalf * 16 + 8] = *(const bf16x8*)(bloptr + k0 + 8);
    __syncthreads();

    bf16x8 ah[4], al[4], bh[4], bl[4];
#pragma unroll
    for (int i = 0; i < 4; i++) {
      ah[i] = *(const bf16x8*)&Ahi_s[wm + i * 16 + m16][kg * 8];
      al[i] = *(const bf16x8*)&Alo_s[wm + i * 16 + m16][kg * 8];
      bh[i] = *(const bf16x8*)&Bhi_s[wn + i * 16 + m16][kg * 8];
      bl[i] = *(const bf16x8*)&Blo_s[wn + i * 16 + m16][kg * 8];
    }
#pragma unroll
    for (int mi = 0; mi < 4; mi++)
#pragma unroll
      for (int ni = 0; ni < 4; ni++) {
        acc[mi][ni] = __builtin_amdgcn_mfma_f32_16x16x32_bf16(ah[mi], bh[ni], acc[mi][ni], 0, 0, 0);
        acc[mi][ni] = __builtin_amdgcn_mfma_f32_16x16x32_bf16(ah[mi], bl[ni], acc[mi][ni], 0, 0, 0);
        acc[mi][ni] = __builtin_amdgcn_mfma_f32_16x16x32_bf16(al[mi], bh[ni], acc[mi][ni], 0, 0, 0);
      }
    __syncthreads();
  }

  // epilogue: store + fused row sum-of-squares
#pragma unroll
  for (int mi = 0; mi < 4; mi++) {
    float ps[4] = {0.f, 0.f, 0.f, 0.f};
#pragma unroll
    for (int ni = 0; ni < 4; ni++) {
      int col = bn0 + wn + ni * 16 + m16;
      float bb = bias ? bias[col] : 0.f;
      f32x4 v = acc[mi][ni];
#pragma unroll
      for (int j = 0; j < 4; j++) {
        float vj = v[j] + bb;
        int row = bm0 + wm + mi * 16 + kg * 4 + j;
        if (row < M) C[(size_t)row * 256 + col] = vj;
        ps[j] += vj * vj;
      }
    }
#pragma unroll
    for (int j = 0; j < 4; j++) {
      float s = ps[j];
      s += __shfl_xor(s, 1);
      s += __shfl_xor(s, 2);
      s += __shfl_xor(s, 4);
      s += __shfl_xor(s, 8);
      if (m16 == 0) {
        int row = bm0 + wm + mi * 16 + kg * 4 + j;
        if (row < M) atomicAdd(&nrm_sq[row], s);
      }
    }
  }
}

// ---------------- CSR build: count / scan / scatter ----------------
__global__ void k_count(const int* __restrict__ dst, int* __restrict__ counts) {
  int e = blockIdx.x * blockDim.x + threadIdx.x;
  if (e >= R_REL * E_EDGES) return;
  int r = e / E_EDGES;
  atomicAdd(&counts[r * N_NODES + dst[e]], 1);
}

__global__ __launch_bounds__(SCAN_B) void k_bsum(const int* __restrict__ counts,
                                                 int* __restrict__ bsum) {
  __shared__ int sh[16];
  int i = blockIdx.x * SCAN_B + threadIdx.x;
  int v = (i < RN) ? counts[i] : 0;
  for (int off = 32; off; off >>= 1) v += __shfl_xor(v, off);
  int wid = threadIdx.x >> 6, lane = threadIdx.x & 63;
  if (lane == 0) sh[wid] = v;
  __syncthreads();
  if (threadIdx.x < 16) {
    int s = sh[threadIdx.x];
    for (int off = 8; off; off >>= 1) s += __shfl_xor(s, off, 16);
    if (threadIdx.x == 0) bsum[blockIdx.x] = s;
  }
}

__global__ __launch_bounds__(256) void k_scanb(const int* __restrict__ bsum,
                                               int* __restrict__ bbase,
                                               int* __restrict__ offsets) {
  __shared__ int s[256];
  int tid = threadIdx.x;
  int v = (tid < SCAN_G) ? bsum[tid] : 0;
  s[tid] = v;
  __syncthreads();
  for (int off = 1; off < 256; off <<= 1) {
    int t2 = (tid >= off) ? s[tid - off] : 0;
    __syncthreads();
    s[tid] += t2;
    __syncthreads();
  }
  if (tid < SCAN_G) bbase[tid] = s[tid] - v;
  if (tid == 255) offsets[RN] = s[255];
}

// cursor may alias counts: each i is read exactly once here before being rewritten.
__global__ __launch_bounds__(SCAN_B) void k_scanlocal(const int* __restrict__ counts_in,
                                                      const int* __restrict__ bbase,
                                                      int* __restrict__ offsets,
                                                      int* __restrict__ cursor) {
  __shared__ int s[SCAN_B];
  int tid = threadIdx.x;
  int i = blockIdx.x * SCAN_B + tid;
  int v = (i < RN) ? counts_in[i] : 0;
  s[tid] = v;
  __syncthreads();
  for (int off = 1; off < SCAN_B; off <<= 1) {
    int t2 = (tid >= off) ? s[tid - off] : 0;
    __syncthreads();
    s[tid] += t2;
    __syncthreads();
  }
  if (i < RN) {
    int excl = s[tid] - v + bbase[blockIdx.x];
    offsets[i] = excl;
    cursor[i]  = excl;
  }
}

__global__ void k_scatter(const int* __restrict__ src, const int* __restrict__ dst,
                          int* cursor, int* __restrict__ edge_src) {
  int e = blockIdx.x * blockDim.x + threadIdx.x;
  if (e >= R_REL * E_EDGES) return;
  int r = e / E_EDGES;
  int pos = atomicAdd(&cursor[r * N_NODES + dst[e]], 1);
  edge_src[pos] = src[e];
}

// ---------------- edge aggregation: one wave per (r, dst-node) ----------------
__global__ __launch_bounds__(256) void k_aggregate(int r,
                                                   const float* __restrict__ hr,
                                                   const float* __restrict__ ht,
                                                   const float* __restrict__ nrm_hr_sq,
                                                   const float* __restrict__ nrm_ht_sq,
                                                   const int* __restrict__ offsets,
                                                   const int* __restrict__ edge_src,
                                                   float* __restrict__ h,
                                                   float* __restrict__ ma) {
  int n    = (int)((blockIdx.x * (size_t)blockDim.x + threadIdx.x) >> 6);
  int lane = threadIdx.x & 63;
  if (n >= N_NODES) return;
  const float4 hd = *(const float4*)(ht + (size_t)n * DIM + lane * 4);
  float ndst = fmaxf(sqrtf(nrm_ht_sq[n]), EPS_C);
  int b     = offsets[r * N_NODES + n];
  int e_end = offsets[r * N_NODES + n + 1];
  float4 acc = {0.f, 0.f, 0.f, 0.f};
  float asum = 0.f;
  for (int e = b; e < e_end; e++) {
    int sn = edge_src[e];
    const float4 hs = *(const float4*)(hr + (size_t)sn * DIM + lane * 4);
    float num = hs.x * hd.x + hs.y * hd.y + hs.z * hd.z + hs.w * hd.w;
    for (int off = 32; off; off >>= 1) num += __shfl_xor(num, off);
    float s = num / (fmaxf(sqrtf(nrm_hr_sq[sn]), EPS_C) * ndst);
    acc.x += s * hs.x; acc.y += s * hs.y; acc.z += s * hs.z; acc.w += s * hs.w;
    asum += s;
  }
  *(float4*)(h + ((size_t)n * R_REL + r) * DIM + lane * 4) = acc;
  if (lane == 0) {
    float cnt = (float)(e_end - b);
    ma[n * R_REL + r] = asum / fmaxf(cnt, 1.0f);
  }
}

// ------- vulnerable nodes: distance-softmax mask + combine, writes out directly ----
__global__ __launch_bounds__(1024) void k_vuln_combine(const float* __restrict__ h,
                                                       const int* __restrict__ cand,
                                                       const float* __restrict__ ma,
                                                       float* __restrict__ out) {
  __shared__ float red[8][16];
  __shared__ float dist2[8];
  __shared__ float sm[4][256];
  int n   = blockIdx.x;
  int tid = threadIdx.x;                       // (r,d): r = tid>>8, d = tid&255
  float hv = h[(size_t)n * 1024 + tid];
  float d2k[8];
#pragma unroll
  for (int k = 0; k < 8; k++) {
    int c = cand[n * 8 + k];
    float hc = h[(size_t)c * 1024 + tid];
    float df = hv - hc;
    d2k[k] = df * df;
  }
  int wid = tid >> 6, lane = tid & 63;
#pragma unroll
  for (int k = 0; k < 8; k++) {
    float v = d2k[k];
    for (int off = 32; off; off >>= 1) v += __shfl_xor(v, off);
    if (lane == 0) red[k][wid] = v;
  }
  __syncthreads();
  if (tid < 128) {
    int k = tid >> 4, w2 = tid & 15;
    float v = red[k][w2];
    for (int off = 8; off; off >>= 1) v += __shfl_xor(v, off, 16);
    if (w2 == 0) dist2[k] = v;
  }
  __syncthreads();
  float dk[8], mn = 1e30f;
#pragma unroll
  for (int k = 0; k < 8; k++) { dk[k] = sqrtf(dist2[k]); mn = fminf(mn, dk[k]); }
  float se = 0.f, att[8];
#pragma unroll
  for (int k = 0; k < 8; k++) { att[k] = expf(mn - dk[k]); se += att[k]; }
  float inv = 1.f / se;
  float acc = 0.f;
#pragma unroll
  for (int k = 0; k < 8; k++) acc += att[k] * inv * d2k[k];
  float masked = hv * expf(-acc);
  float m0 = ma[n * 4 + 0], m1 = ma[n * 4 + 1], m2 = ma[n * 4 + 2], m3 = ma[n * 4 + 3];
  float mx = fmaxf(fmaxf(m0, m1), fmaxf(m2, m3));
  float w0 = expf(m0 - mx), w1 = expf(m1 - mx), w2f = expf(m2 - mx), w3 = expf(m3 - mx);
  float winv = 1.f / (w0 + w1 + w2f + w3);
  float wr = (tid < 256) ? w0 : (tid < 512) ? w1 : (tid < 768) ? w2f : w3;
  sm[tid >> 8][tid & 255] = wr * winv * masked;
  __syncthreads();
  if (tid < 256)
    out[(size_t)n * 256 + tid] = sm[0][tid] + sm[1][tid] + sm[2][tid] + sm[3][tid];
}

// ---------------- combine for non-vulnerable nodes ----------------
__global__ __launch_bounds__(256) void k_combine_rest(const float* __restrict__ h,
                                                      const float* __restrict__ ma,
                                                      float* __restrict__ out) {
  int n = NV_VUL + blockIdx.x;
  int d = threadIdx.x;
  float m0 = ma[n * 4 + 0], m1 = ma[n * 4 + 1], m2 = ma[n * 4 + 2], m3 = ma[n * 4 + 3];
  float mx = fmaxf(fmaxf(m0, m1), fmaxf(m2, m3));
  float w0 = expf(m0 - mx), w1 = expf(m1 - mx), w2 = expf(m2 - mx), w3 = expf(m3 - mx);
  float inv = 1.f / (w0 + w1 + w2 + w3);
  const float* hs = h + (size_t)n * 1024;
  float v = w0 * hs[d] + w1 * hs[256 + d] + w2 * hs[512 + d] + w3 * hs[768 + d];
  out[(size_t)n * 256 + d] = v * inv;
}

// ---------------- diagnostic fallback: encode ws_size(MB) into out[0] ----------
__global__ void k_fallback(float* __restrict__ out, int out_size, float wsmb) {
  int i = blockIdx.x * blockDim.x + threadIdx.x;
  if (i < out_size) out[i] = (i == 0) ? wsmb : 0.f;
}

extern "C" void kernel_launch(void* const* d_in, const int* in_sizes, int n_in,
                              void* d_out, int out_size, void* d_ws, size_t ws_size,
                              hipStream_t stream) {
  const float* x   = (const float*)d_in[0];
  const float* We  = (const float*)d_in[1];
  const float* Wn  = (const float*)d_in[2];
  const float* bnb = (const float*)d_in[3];
  const int* src   = (const int*)d_in[4];
  const int* dst   = (const int*)d_in[5];
  const int* cand  = (const int*)d_in[6];
  float* out = (float*)d_out;

  char* ws = (char*)d_ws;
  size_t off = 0;
  auto alloc = [&](size_t bytes) -> void* {
    void* p = ws + off;
    off += (bytes + 255) & ~(size_t)255;
    return p;
  };
  float* ht         = (float*)alloc((size_t)N_NODES * DIM * 4);            // 51.2 MB
  float* h          = (float*)alloc((size_t)N_NODES * R_REL * DIM * 4);    // 204.8 MB
  float* ma         = (float*)alloc((size_t)N_NODES * R_REL * 4);
  float* nrm_ht_sq  = (float*)alloc((size_t)N_NODES * 4);
  float* nrm_hr_sq  = (float*)alloc((size_t)N_NODES * 4);
  int*   counts     = (int*)alloc((size_t)RN * 4);                         // aliased as cursor
  int*   offsets    = (int*)alloc((size_t)(RN + 1) * 4);
  int*   bsum       = (int*)alloc((size_t)SCAN_G * 4);
  int*   bbase      = (int*)alloc((size_t)SCAN_G * 4);
  int*   edge_src   = (int*)alloc((size_t)R_REL * E_EDGES * 4);            // 8 MB
  short* Bthi       = (short*)alloc((size_t)5 * 65536 * 2);                // 0.66 MB
  short* Btlo       = (short*)alloc((size_t)5 * 65536 * 2);                // 0.66 MB
  size_t required = off;
  (void)in_sizes; (void)n_in;

  if (ws_size < required) {
    k_fallback<<<(out_size + 255) / 256, 256, 0, stream>>>(out, out_size,
                                                           (float)(ws_size >> 20));
    return;
  }

  float* hr = out;               // d_out doubles as the per-relation projection buffer
  int* cursor = counts;          // safe alias (see k_scanlocal)

  hipMemsetAsync(counts, 0, (size_t)RN * 4, stream);
  hipMemsetAsync(nrm_ht_sq, 0, (size_t)N_NODES * 4, stream);

  // weight split+transpose (tiny)
  k_convert_w<<<dim3(4, 4, 5), 256, 0, stream>>>(Wn, We, Bthi, Btlo);

  dim3 gemm_grid((N_NODES + GBM - 1) / GBM, DIM / GBN);

  // ht = x @ Wn + bn (split-bf16 MFMA), fused row sumsq
  k_gemm_mfma<<<gemm_grid, 256, 0, stream>>>(x, Bthi, Btlo, bnb, ht, nrm_ht_sq, N_NODES);

  // CSR by (r, dst)
  k_count<<<(R_REL * E_EDGES + 255) / 256, 256, 0, stream>>>(dst, counts);
  k_bsum<<<SCAN_G, SCAN_B, 0, stream>>>(counts, bsum);
  k_scanb<<<1, 256, 0, stream>>>(bsum, bbase, offsets);
  k_scanlocal<<<SCAN_G, SCAN_B, 0, stream>>>(counts, bbase, offsets, cursor);
  k_scatter<<<(R_REL * E_EDGES + 255) / 256, 256, 0, stream>>>(src, dst, cursor, edge_src);

  // per relation: hr = x @ We[r] (MFMA); aggregate into h[:, r, :], ma[:, r]
  for (int r = 0; r < R_REL; r++) {
    hipMemsetAsync(nrm_hr_sq, 0, (size_t)N_NODES * 4, stream);
    k_gemm_mfma<<<gemm_grid, 256, 0, stream>>>(x, Bthi + (size_t)(1 + r) * 65536,
                                               Btlo + (size_t)(1 + r) * 65536,
                                               nullptr, hr, nrm_hr_sq, N_NODES);
    k_aggregate<<<(N_NODES * 64 + 255) / 256, 256, 0, stream>>>(
        r, hr, ht, nrm_hr_sq, nrm_ht_sq, offsets, edge_src, h, ma);
  }

  // vulnerable nodes: mask + combine (reads pristine h, writes out rows [0, NV))
  k_vuln_combine<<<NV_VUL, 1024, 0, stream>>>(h, cand, ma, out);

  // non-vulnerable nodes: combine (writes out rows [NV, N))
  k_combine_rest<<<N_NODES - NV_VUL, 256, 0, stream>>>(h, ma, out);
}

// Round 4
// 922.779 us; speedup vs baseline: 1.4327x; 1.1261x over previous
//
#include <hip/hip_runtime.h>

#define N_NODES 50000
#define DIM     256
#define R_REL   4
#define E_EDGES 500000
#define NV_VUL  10000
#define K_CAND  8
#define EPS_C   1e-8f
#define RN      (R_REL * N_NODES)            // 200000
#define SCAN_B  1024
#define SCAN_G  ((RN + SCAN_B - 1) / SCAN_B) // 196

typedef short bf16x8 __attribute__((ext_vector_type(8)));
typedef float f32x4  __attribute__((ext_vector_type(4)));

__device__ __forceinline__ unsigned short f2bf_rne(float f) {
  unsigned u = __builtin_bit_cast(unsigned, f);
  unsigned r = (u + 0x7FFFu + ((u >> 16) & 1u)) >> 16;
  return (unsigned short)r;
}
__device__ __forceinline__ float bf2f(unsigned short h) {
  unsigned u = ((unsigned)h) << 16;
  return __builtin_bit_cast(float, u);
}
__device__ __forceinline__ void cvt8(float4 a, float4 b, bf16x8* h, bf16x8* l) {
  float f[8] = {a.x, a.y, a.z, a.w, b.x, b.y, b.z, b.w};
  bf16x8 hh, ll;
#pragma unroll
  for (int i = 0; i < 8; i++) {
    unsigned short hv = f2bf_rne(f[i]);
    hh[i] = (short)hv;
    ll[i] = (short)f2bf_rne(f[i] - bf2f(hv));
  }
  *h = hh; *l = ll;
}

// ---- weight prep: Bt_hi[w][n][k], Bt_lo[w][n][k] = split(W_w[k][n]) ----
__global__ __launch_bounds__(256) void k_convert_w(const float* __restrict__ Wn,
                                                   const float* __restrict__ We,
                                                   short* __restrict__ Bthi,
                                                   short* __restrict__ Btlo) {
  __shared__ float tile[64][65];
  int w  = blockIdx.z;                    // 0 = Wn, 1..4 = We[w-1]
  int k0 = blockIdx.x * 64, n0 = blockIdx.y * 64;
  const float* W = (w == 0) ? Wn : We + (size_t)(w - 1) * 65536;
  int tx = threadIdx.x & 63, ty = threadIdx.x >> 6;
  for (int i = ty; i < 64; i += 4)
    tile[i][tx] = W[(size_t)(k0 + i) * 256 + n0 + tx];
  __syncthreads();
  for (int i = ty; i < 64; i += 4) {
    float f = tile[tx][i];                // = W[k0+tx][n0+i]
    unsigned short h = f2bf_rne(f);
    size_t o = (size_t)w * 65536 + (size_t)(n0 + i) * 256 + k0 + tx;
    Bthi[o] = (short)h;
    Btlo[o] = (short)f2bf_rne(f - bf2f(h));
  }
}

// ---- split-bf16 MFMA GEMM: C[M x 256] = A[M x 256] @ W (+bias), fused row sumsq ----
#define GBM 128
#define GBN 128
#define GBK 32
__global__ __launch_bounds__(256) void k_gemm_mfma(const float* __restrict__ A,
                                                   const short* __restrict__ Bthi,
                                                   const short* __restrict__ Btlo,
                                                   const float* __restrict__ bias,
                                                   float* __restrict__ C,
                                                   float* __restrict__ nrm_sq,
                                                   int M) {
  __shared__ short Ahi_s[128][GBK + 8];
  __shared__ short Alo_s[128][GBK + 8];
  __shared__ short Bhi_s[128][GBK + 8];
  __shared__ short Blo_s[128][GBK + 8];
  const int t    = threadIdx.x;
  const int bm0  = blockIdx.x * GBM;
  const int bn0  = blockIdx.y * GBN;
  const int wave = t >> 6, lane = t & 63;
  const int wm   = (wave >> 1) * 64, wn = (wave & 1) * 64;
  const int m16  = lane & 15, kg = lane >> 4;

  f32x4 acc[4][4] = {};

  const int srow  = t >> 1;
  const int shalf = t & 1;
  int agrow = bm0 + srow; if (agrow >= M) agrow = M - 1;
  const float* aptr   = A    + (size_t)agrow * 256 + shalf * 16;
  const short* bhiptr = Bthi + (size_t)(bn0 + srow) * 256 + shalf * 16;
  const short* bloptr = Btlo + (size_t)(bn0 + srow) * 256 + shalf * 16;

  for (int k0 = 0; k0 < DIM; k0 += GBK) {
    float4 av0 = *(const float4*)(aptr + k0);
    float4 av1 = *(const float4*)(aptr + k0 + 4);
    float4 av2 = *(const float4*)(aptr + k0 + 8);
    float4 av3 = *(const float4*)(aptr + k0 + 12);
    bf16x8 h0, l0, h1, l1;
    cvt8(av0, av1, &h0, &l0);
    cvt8(av2, av3, &h1, &l1);
    *(bf16x8*)&Ahi_s[srow][shalf * 16 + 0] = h0;
    *(bf16x8*)&Ahi_s[srow][shalf * 16 + 8] = h1;
    *(bf16x8*)&Alo_s[srow][shalf * 16 + 0] = l0;
    *(bf16x8*)&Alo_s[srow][shalf * 16 + 8] = l1;
    *(bf16x8*)&Bhi_s[srow][shalf * 16 + 0] = *(const bf16x8*)(bhiptr + k0);
    *(bf16x8*)&Bhi_s[srow][shalf * 16 + 8] = *(const bf16x8*)(bhiptr + k0 + 8);
    *(bf16x8*)&Blo_s[srow][shalf * 16 + 0] = *(const bf16x8*)(bloptr + k0);
    *(bf16x8*)&Blo_s[srow][shalf * 16 + 8] = *(const bf16x8*)(bloptr + k0 + 8);
    __syncthreads();

    bf16x8 ah[4], al[4], bh[4], bl[4];
#pragma unroll
    for (int i = 0; i < 4; i++) {
      ah[i] = *(const bf16x8*)&Ahi_s[wm + i * 16 + m16][kg * 8];
      al[i] = *(const bf16x8*)&Alo_s[wm + i * 16 + m16][kg * 8];
      bh[i] = *(const bf16x8*)&Bhi_s[wn + i * 16 + m16][kg * 8];
      bl[i] = *(const bf16x8*)&Blo_s[wn + i * 16 + m16][kg * 8];
    }
#pragma unroll
    for (int mi = 0; mi < 4; mi++)
#pragma unroll
      for (int ni = 0; ni < 4; ni++) {
        acc[mi][ni] = __builtin_amdgcn_mfma_f32_16x16x32_bf16(ah[mi], bh[ni], acc[mi][ni], 0, 0, 0);
        acc[mi][ni] = __builtin_amdgcn_mfma_f32_16x16x32_bf16(ah[mi], bl[ni], acc[mi][ni], 0, 0, 0);
        acc[mi][ni] = __builtin_amdgcn_mfma_f32_16x16x32_bf16(al[mi], bh[ni], acc[mi][ni], 0, 0, 0);
      }
    __syncthreads();
  }

#pragma unroll
  for (int mi = 0; mi < 4; mi++) {
    float ps[4] = {0.f, 0.f, 0.f, 0.f};
#pragma unroll
    for (int ni = 0; ni < 4; ni++) {
      int col = bn0 + wn + ni * 16 + m16;
      float bb = bias ? bias[col] : 0.f;
      f32x4 v = acc[mi][ni];
#pragma unroll
      for (int j = 0; j < 4; j++) {
        float vj = v[j] + bb;
        int row = bm0 + wm + mi * 16 + kg * 4 + j;
        if (row < M) C[(size_t)row * 256 + col] = vj;
        ps[j] += vj * vj;
      }
    }
#pragma unroll
    for (int j = 0; j < 4; j++) {
      float s = ps[j];
      s += __shfl_xor(s, 1);
      s += __shfl_xor(s, 2);
      s += __shfl_xor(s, 4);
      s += __shfl_xor(s, 8);
      if (m16 == 0) {
        int row = bm0 + wm + mi * 16 + kg * 4 + j;
        if (row < M) atomicAdd(&nrm_sq[row], s);
      }
    }
  }
}

// ---- in-place: nrm_sq[i] -> 1 / max(sqrt(nrm_sq[i]), EPS) ----
__global__ __launch_bounds__(256) void k_rnorm(float* __restrict__ sq, int M) {
  int i = blockIdx.x * blockDim.x + threadIdx.x;
  if (i < M) sq[i] = 1.0f / fmaxf(sqrtf(sq[i]), EPS_C);
}

// ---------------- CSR build: count / scan / scatter ----------------
__global__ void k_count(const int* __restrict__ dst, int* __restrict__ counts) {
  int e = blockIdx.x * blockDim.x + threadIdx.x;
  if (e >= R_REL * E_EDGES) return;
  int r = e / E_EDGES;
  atomicAdd(&counts[r * N_NODES + dst[e]], 1);
}

__global__ __launch_bounds__(SCAN_B) void k_bsum(const int* __restrict__ counts,
                                                 int* __restrict__ bsum) {
  __shared__ int sh[16];
  int i = blockIdx.x * SCAN_B + threadIdx.x;
  int v = (i < RN) ? counts[i] : 0;
  for (int off = 32; off; off >>= 1) v += __shfl_xor(v, off);
  int wid = threadIdx.x >> 6, lane = threadIdx.x & 63;
  if (lane == 0) sh[wid] = v;
  __syncthreads();
  if (threadIdx.x < 16) {
    int s = sh[threadIdx.x];
    for (int off = 8; off; off >>= 1) s += __shfl_xor(s, off, 16);
    if (threadIdx.x == 0) bsum[blockIdx.x] = s;
  }
}

__global__ __launch_bounds__(256) void k_scanb(const int* __restrict__ bsum,
                                               int* __restrict__ bbase,
                                               int* __restrict__ offsets) {
  __shared__ int s[256];
  int tid = threadIdx.x;
  int v = (tid < SCAN_G) ? bsum[tid] : 0;
  s[tid] = v;
  __syncthreads();
  for (int off = 1; off < 256; off <<= 1) {
    int t2 = (tid >= off) ? s[tid - off] : 0;
    __syncthreads();
    s[tid] += t2;
    __syncthreads();
  }
  if (tid < SCAN_G) bbase[tid] = s[tid] - v;
  if (tid == 255) offsets[RN] = s[255];
}

__global__ __launch_bounds__(SCAN_B) void k_scanlocal(const int* __restrict__ counts_in,
                                                      const int* __restrict__ bbase,
                                                      int* __restrict__ offsets,
                                                      int* __restrict__ cursor) {
  __shared__ int s[SCAN_B];
  int tid = threadIdx.x;
  int i = blockIdx.x * SCAN_B + tid;
  int v = (i < RN) ? counts_in[i] : 0;
  s[tid] = v;
  __syncthreads();
  for (int off = 1; off < SCAN_B; off <<= 1) {
    int t2 = (tid >= off) ? s[tid - off] : 0;
    __syncthreads();
    s[tid] += t2;
    __syncthreads();
  }
  if (i < RN) {
    int excl = s[tid] - v + bbase[blockIdx.x];
    offsets[i] = excl;
    cursor[i]  = excl;
  }
}

__global__ void k_scatter(const int* __restrict__ src, const int* __restrict__ dst,
                          int* cursor, int* __restrict__ edge_src) {
  int e = blockIdx.x * blockDim.x + threadIdx.x;
  if (e >= R_REL * E_EDGES) return;
  int r = e / E_EDGES;
  int pos = atomicAdd(&cursor[r * N_NODES + dst[e]], 1);
  edge_src[pos] = src[e];
}

// ------ edge aggregation: one wave per (r, dst-node), software-pipelined ------
__global__ __launch_bounds__(256) void k_aggregate(int r,
                                                   const float* __restrict__ hr,
                                                   const float* __restrict__ ht,
                                                   const float* __restrict__ rn_hr,
                                                   const float* __restrict__ rn_ht,
                                                   const int* __restrict__ offsets,
                                                   const int* __restrict__ edge_src,
                                                   float* __restrict__ h,
                                                   float* __restrict__ ma) {
  int n    = (int)((blockIdx.x * (size_t)blockDim.x + threadIdx.x) >> 6);
  int lane = threadIdx.x & 63;
  if (n >= N_NODES) return;
  const float4 hd = *(const float4*)(ht + (size_t)n * DIM + lane * 4);
  float rd = rn_ht[n];
  int b     = offsets[r * N_NODES + n];
  int e_end = offsets[r * N_NODES + n + 1];
  float4 acc = {0.f, 0.f, 0.f, 0.f};
  float asum = 0.f;
  float4 hs_n = {0.f, 0.f, 0.f, 0.f};
  float rs_n = 0.f;
  if (b < e_end) {
    int sn = edge_src[b];
    hs_n = *(const float4*)(hr + (size_t)sn * DIM + lane * 4);
    rs_n = rn_hr[sn];
  }
  for (int e = b; e < e_end; e++) {
    float4 hs = hs_n;
    float rs = rs_n;
    if (e + 1 < e_end) {
      int sn2 = edge_src[e + 1];
      hs_n = *(const float4*)(hr + (size_t)sn2 * DIM + lane * 4);
      rs_n = rn_hr[sn2];
    }
    float num = hs.x * hd.x + hs.y * hd.y + hs.z * hd.z + hs.w * hd.w;
    for (int off = 32; off; off >>= 1) num += __shfl_xor(num, off);
    float s = num * rs * rd;
    acc.x += s * hs.x; acc.y += s * hs.y; acc.z += s * hs.z; acc.w += s * hs.w;
    asum += s;
  }
  *(float4*)(h + ((size_t)n * R_REL + r) * DIM + lane * 4) = acc;
  if (lane == 0) {
    float cnt = (float)(e_end - b);
    ma[n * R_REL + r] = asum / fmaxf(cnt, 1.0f);
  }
}

// ------- vulnerable nodes: mask + combine, 256 threads, float4-vectorized -------
__global__ __launch_bounds__(256) void k_vuln_combine(const float* __restrict__ h,
                                                      const int* __restrict__ cand,
                                                      const float* __restrict__ ma,
                                                      float* __restrict__ out) {
  __shared__ float red[8][4];
  __shared__ float dist2s[8];
  __shared__ float sm[1024];
  int n   = blockIdx.x;
  int tid = threadIdx.x;                       // owns elements tid*4 .. tid*4+3
  const float4 hv = *(const float4*)(h + (size_t)n * 1024 + tid * 4);
  float4 hc[8];
#pragma unroll
  for (int k = 0; k < 8; k++) {
    int c = cand[n * 8 + k];
    hc[k] = *(const float4*)(h + (size_t)c * 1024 + tid * 4);
  }
  float4 d2[8];
  int wid = tid >> 6, lane = tid & 63;
#pragma unroll
  for (int k = 0; k < 8; k++) {
    float4 df;
    df.x = hv.x - hc[k].x; df.y = hv.y - hc[k].y;
    df.z = hv.z - hc[k].z; df.w = hv.w - hc[k].w;
    d2[k].x = df.x * df.x; d2[k].y = df.y * df.y;
    d2[k].z = df.z * df.z; d2[k].w = df.w * df.w;
    float v = d2[k].x + d2[k].y + d2[k].z + d2[k].w;
    for (int off = 32; off; off >>= 1) v += __shfl_xor(v, off);
    if (lane == 0) red[k][wid] = v;
  }
  __syncthreads();
  if (tid < 32) {
    int k = tid >> 2, w2 = tid & 3;
    float v = red[k][w2];
    v += __shfl_xor(v, 1, 4);
    v += __shfl_xor(v, 2, 4);
    if (w2 == 0) dist2s[k] = v;
  }
  __syncthreads();
  float dk[8], mn = 1e30f;
#pragma unroll
  for (int k = 0; k < 8; k++) { dk[k] = sqrtf(dist2s[k]); mn = fminf(mn, dk[k]); }
  float se = 0.f, att[8];
#pragma unroll
  for (int k = 0; k < 8; k++) { att[k] = expf(mn - dk[k]); se += att[k]; }
  float inv = 1.f / se;
  float4 accv = {0.f, 0.f, 0.f, 0.f};
#pragma unroll
  for (int k = 0; k < 8; k++) {
    float a = att[k] * inv;
    accv.x += a * d2[k].x; accv.y += a * d2[k].y;
    accv.z += a * d2[k].z; accv.w += a * d2[k].w;
  }
  // combine weights
  float m0 = ma[n * 4 + 0], m1 = ma[n * 4 + 1], m2 = ma[n * 4 + 2], m3 = ma[n * 4 + 3];
  float mx = fmaxf(fmaxf(m0, m1), fmaxf(m2, m3));
  float w0 = expf(m0 - mx), w1 = expf(m1 - mx), w2f = expf(m2 - mx), w3 = expf(m3 - mx);
  float winv = 1.f / (w0 + w1 + w2f + w3);
  float wr = (tid < 64) ? w0 : (tid < 128) ? w1 : (tid < 192) ? w2f : w3;  // r = tid/64
  float c = wr * winv;
  float4 o;
  o.x = c * hv.x * expf(-accv.x);
  o.y = c * hv.y * expf(-accv.y);
  o.z = c * hv.z * expf(-accv.z);
  o.w = c * hv.w * expf(-accv.w);
  *(float4*)&sm[tid * 4] = o;
  __syncthreads();
  if (tid < 256) {
    float v = sm[tid] + sm[256 + tid] + sm[512 + tid] + sm[768 + tid];
    out[(size_t)n * 256 + tid] = v;
  }
}

// ---------------- combine for non-vulnerable nodes ----------------
__global__ __launch_bounds__(256) void k_combine_rest(const float* __restrict__ h,
                                                      const float* __restrict__ ma,
                                                      float* __restrict__ out) {
  int n = NV_VUL + blockIdx.x;
  int d = threadIdx.x;
  float m0 = ma[n * 4 + 0], m1 = ma[n * 4 + 1], m2 = ma[n * 4 + 2], m3 = ma[n * 4 + 3];
  float mx = fmaxf(fmaxf(m0, m1), fmaxf(m2, m3));
  float w0 = expf(m0 - mx), w1 = expf(m1 - mx), w2 = expf(m2 - mx), w3 = expf(m3 - mx);
  float inv = 1.f / (w0 + w1 + w2 + w3);
  const float* hs = h + (size_t)n * 1024;
  float v = w0 * hs[d] + w1 * hs[256 + d] + w2 * hs[512 + d] + w3 * hs[768 + d];
  out[(size_t)n * 256 + d] = v * inv;
}

// ---------------- diagnostic fallback ----------------
__global__ void k_fallback(float* __restrict__ out, int out_size, float wsmb) {
  int i = blockIdx.x * blockDim.x + threadIdx.x;
  if (i < out_size) out[i] = (i == 0) ? wsmb : 0.f;
}

extern "C" void kernel_launch(void* const* d_in, const int* in_sizes, int n_in,
                              void* d_out, int out_size, void* d_ws, size_t ws_size,
                              hipStream_t stream) {
  const float* x   = (const float*)d_in[0];
  const float* We  = (const float*)d_in[1];
  const float* Wn  = (const float*)d_in[2];
  const float* bnb = (const float*)d_in[3];
  const int* src   = (const int*)d_in[4];
  const int* dst   = (const int*)d_in[5];
  const int* cand  = (const int*)d_in[6];
  float* out = (float*)d_out;

  char* ws = (char*)d_ws;
  size_t off = 0;
  auto alloc = [&](size_t bytes) -> void* {
    void* p = ws + off;
    off += (bytes + 255) & ~(size_t)255;
    return p;
  };
  float* ht         = (float*)alloc((size_t)N_NODES * DIM * 4);            // 51.2 MB
  float* h          = (float*)alloc((size_t)N_NODES * R_REL * DIM * 4);    // 204.8 MB
  float* ma         = (float*)alloc((size_t)N_NODES * R_REL * 4);
  float* nrm_ht_sq  = (float*)alloc((size_t)N_NODES * 4);                  // -> rnorm in place
  float* nrm_hr_sq  = (float*)alloc((size_t)N_NODES * 4);                  // -> rnorm in place
  int*   counts     = (int*)alloc((size_t)RN * 4);                         // aliased as cursor
  int*   offsets    = (int*)alloc((size_t)(RN + 1) * 4);
  int*   bsum       = (int*)alloc((size_t)SCAN_G * 4);
  int*   bbase      = (int*)alloc((size_t)SCAN_G * 4);
  int*   edge_src   = (int*)alloc((size_t)R_REL * E_EDGES * 4);            // 8 MB
  short* Bthi       = (short*)alloc((size_t)5 * 65536 * 2);                // 0.66 MB
  short* Btlo       = (short*)alloc((size_t)5 * 65536 * 2);                // 0.66 MB
  size_t required = off;
  (void)in_sizes; (void)n_in;

  if (ws_size < required) {
    k_fallback<<<(out_size + 255) / 256, 256, 0, stream>>>(out, out_size,
                                                           (float)(ws_size >> 20));
    return;
  }

  float* hr = out;               // d_out doubles as the per-relation projection buffer
  int* cursor = counts;          // safe alias (see k_scanlocal)

  hipMemsetAsync(counts, 0, (size_t)RN * 4, stream);
  hipMemsetAsync(nrm_ht_sq, 0, (size_t)N_NODES * 4, stream);

  k_convert_w<<<dim3(4, 4, 5), 256, 0, stream>>>(Wn, We, Bthi, Btlo);

  dim3 gemm_grid((N_NODES + GBM - 1) / GBM, DIM / GBN);

  // ht = x @ Wn + bn (split-bf16 MFMA), fused row sumsq -> reciprocal norm
  k_gemm_mfma<<<gemm_grid, 256, 0, stream>>>(x, Bthi, Btlo, bnb, ht, nrm_ht_sq, N_NODES);
  k_rnorm<<<(N_NODES + 255) / 256, 256, 0, stream>>>(nrm_ht_sq, N_NODES);

  // CSR by (r, dst)
  k_count<<<(R_REL * E_EDGES + 255) / 256, 256, 0, stream>>>(dst, counts);
  k_bsum<<<SCAN_G, SCAN_B, 0, stream>>>(counts, bsum);
  k_scanb<<<1, 256, 0, stream>>>(bsum, bbase, offsets);
  k_scanlocal<<<SCAN_G, SCAN_B, 0, stream>>>(counts, bbase, offsets, cursor);
  k_scatter<<<(R_REL * E_EDGES + 255) / 256, 256, 0, stream>>>(src, dst, cursor, edge_src);

  // per relation: hr = x @ We[r] (MFMA); aggregate into h[:, r, :], ma[:, r]
  for (int r = 0; r < R_REL; r++) {
    hipMemsetAsync(nrm_hr_sq, 0, (size_t)N_NODES * 4, stream);
    k_gemm_mfma<<<gemm_grid, 256, 0, stream>>>(x, Bthi + (size_t)(1 + r) * 65536,
                                               Btlo + (size_t)(1 + r) * 65536,
                                               nullptr, hr, nrm_hr_sq, N_NODES);
    k_rnorm<<<(N_NODES + 255) / 256, 256, 0, stream>>>(nrm_hr_sq, N_NODES);
    k_aggregate<<<(N_NODES * 64 + 255) / 256, 256, 0, stream>>>(
        r, hr, ht, nrm_hr_sq, nrm_ht_sq, offsets, edge_src, h, ma);
  }

  // vulnerable nodes: mask + combine (reads pristine h, writes out rows [0, NV))
  k_vuln_combine<<<NV_VUL, 256, 0, stream>>>(h, cand, ma, out);

  // non-vulnerable nodes: combine (writes out rows [NV, N))
  k_combine_rest<<<N_NODES - NV_VUL, 256, 0, stream>>>(h, ma, out);
}

// Round 5
// 735.751 us; speedup vs baseline: 1.7969x; 1.2542x over previous
//
#include <hip/hip_runtime.h>

#define N_NODES 50000
#define DIM     256
#define R_REL   4
#define E_EDGES 500000
#define NV_VUL  10000
#define K_CAND  8
#define EPS_C   1e-8f
#define RN      (R_REL * N_NODES)            // 200000
#define NB      196                          // buckets per relation (256 nodes each)
#define TB      (R_REL * NB)                 // 784 total buckets
#define BCAP    5120                         // capacity per bucket (mean 2551)
#define EPB     8192                         // edges per k_bin block

typedef short bf16x8 __attribute__((ext_vector_type(8)));
typedef float f32x4  __attribute__((ext_vector_type(4)));

__device__ __forceinline__ unsigned short f2bf_rne(float f) {
  unsigned u = __builtin_bit_cast(unsigned, f);
  unsigned r = (u + 0x7FFFu + ((u >> 16) & 1u)) >> 16;
  return (unsigned short)r;
}
__device__ __forceinline__ float bf2f(unsigned short h) {
  unsigned u = ((unsigned)h) << 16;
  return __builtin_bit_cast(float, u);
}
__device__ __forceinline__ void cvt8(float4 a, float4 b, bf16x8* h, bf16x8* l) {
  float f[8] = {a.x, a.y, a.z, a.w, b.x, b.y, b.z, b.w};
  bf16x8 hh, ll;
#pragma unroll
  for (int i = 0; i < 8; i++) {
    unsigned short hv = f2bf_rne(f[i]);
    hh[i] = (short)hv;
    ll[i] = (short)f2bf_rne(f[i] - bf2f(hv));
  }
  *h = hh; *l = ll;
}

// ---- weight prep: Bt_hi[w][n][k], Bt_lo[w][n][k] = split(W_w[k][n]) ----
__global__ __launch_bounds__(256) void k_convert_w(const float* __restrict__ Wn,
                                                   const float* __restrict__ We,
                                                   short* __restrict__ Bthi,
                                                   short* __restrict__ Btlo) {
  __shared__ float tile[64][65];
  int w  = blockIdx.z;                    // 0 = Wn, 1..4 = We[w-1]
  int k0 = blockIdx.x * 64, n0 = blockIdx.y * 64;
  const float* W = (w == 0) ? Wn : We + (size_t)(w - 1) * 65536;
  int tx = threadIdx.x & 63, ty = threadIdx.x >> 6;
  for (int i = ty; i < 64; i += 4)
    tile[i][tx] = W[(size_t)(k0 + i) * 256 + n0 + tx];
  __syncthreads();
  for (int i = ty; i < 64; i += 4) {
    float f = tile[tx][i];                // = W[k0+tx][n0+i]
    unsigned short h = f2bf_rne(f);
    size_t o = (size_t)w * 65536 + (size_t)(n0 + i) * 256 + k0 + tx;
    Bthi[o] = (short)h;
    Btlo[o] = (short)f2bf_rne(f - bf2f(h));
  }
}

// ---- split-bf16 MFMA GEMM: C[M x 256] = A[M x 256] @ W (+bias), fused row sumsq ----
#define GBM 128
#define GBN 128
#define GBK 32
__global__ __launch_bounds__(256) void k_gemm_mfma(const float* __restrict__ A,
                                                   const short* __restrict__ Bthi,
                                                   const short* __restrict__ Btlo,
                                                   const float* __restrict__ bias,
                                                   float* __restrict__ C,
                                                   float* __restrict__ nrm_sq,
                                                   int M) {
  __shared__ short Ahi_s[128][GBK + 8];
  __shared__ short Alo_s[128][GBK + 8];
  __shared__ short Bhi_s[128][GBK + 8];
  __shared__ short Blo_s[128][GBK + 8];
  const int t    = threadIdx.x;
  const int bm0  = blockIdx.x * GBM;
  const int bn0  = blockIdx.y * GBN;
  const int wave = t >> 6, lane = t & 63;
  const int wm   = (wave >> 1) * 64, wn = (wave & 1) * 64;
  const int m16  = lane & 15, kg = lane >> 4;

  f32x4 acc[4][4] = {};

  const int srow  = t >> 1;
  const int shalf = t & 1;
  int agrow = bm0 + srow; if (agrow >= M) agrow = M - 1;
  const float* aptr   = A    + (size_t)agrow * 256 + shalf * 16;
  const short* bhiptr = Bthi + (size_t)(bn0 + srow) * 256 + shalf * 16;
  const short* bloptr = Btlo + (size_t)(bn0 + srow) * 256 + shalf * 16;

  for (int k0 = 0; k0 < DIM; k0 += GBK) {
    float4 av0 = *(const float4*)(aptr + k0);
    float4 av1 = *(const float4*)(aptr + k0 + 4);
    float4 av2 = *(const float4*)(aptr + k0 + 8);
    float4 av3 = *(const float4*)(aptr + k0 + 12);
    bf16x8 h0, l0, h1, l1;
    cvt8(av0, av1, &h0, &l0);
    cvt8(av2, av3, &h1, &l1);
    *(bf16x8*)&Ahi_s[srow][shalf * 16 + 0] = h0;
    *(bf16x8*)&Ahi_s[srow][shalf * 16 + 8] = h1;
    *(bf16x8*)&Alo_s[srow][shalf * 16 + 0] = l0;
    *(bf16x8*)&Alo_s[srow][shalf * 16 + 8] = l1;
    *(bf16x8*)&Bhi_s[srow][shalf * 16 + 0] = *(const bf16x8*)(bhiptr + k0);
    *(bf16x8*)&Bhi_s[srow][shalf * 16 + 8] = *(const bf16x8*)(bhiptr + k0 + 8);
    *(bf16x8*)&Blo_s[srow][shalf * 16 + 0] = *(const bf16x8*)(bloptr + k0);
    *(bf16x8*)&Blo_s[srow][shalf * 16 + 8] = *(const bf16x8*)(bloptr + k0 + 8);
    __syncthreads();

    bf16x8 ah[4], al[4], bh[4], bl[4];
#pragma unroll
    for (int i = 0; i < 4; i++) {
      ah[i] = *(const bf16x8*)&Ahi_s[wm + i * 16 + m16][kg * 8];
      al[i] = *(const bf16x8*)&Alo_s[wm + i * 16 + m16][kg * 8];
      bh[i] = *(const bf16x8*)&Bhi_s[wn + i * 16 + m16][kg * 8];
      bl[i] = *(const bf16x8*)&Blo_s[wn + i * 16 + m16][kg * 8];
    }
#pragma unroll
    for (int mi = 0; mi < 4; mi++)
#pragma unroll
      for (int ni = 0; ni < 4; ni++) {
        acc[mi][ni] = __builtin_amdgcn_mfma_f32_16x16x32_bf16(ah[mi], bh[ni], acc[mi][ni], 0, 0, 0);
        acc[mi][ni] = __builtin_amdgcn_mfma_f32_16x16x32_bf16(ah[mi], bl[ni], acc[mi][ni], 0, 0, 0);
        acc[mi][ni] = __builtin_amdgcn_mfma_f32_16x16x32_bf16(al[mi], bh[ni], acc[mi][ni], 0, 0, 0);
      }
    __syncthreads();
  }

#pragma unroll
  for (int mi = 0; mi < 4; mi++) {
    float ps[4] = {0.f, 0.f, 0.f, 0.f};
#pragma unroll
    for (int ni = 0; ni < 4; ni++) {
      int col = bn0 + wn + ni * 16 + m16;
      float bb = bias ? bias[col] : 0.f;
      f32x4 v = acc[mi][ni];
#pragma unroll
      for (int j = 0; j < 4; j++) {
        float vj = v[j] + bb;
        int row = bm0 + wm + mi * 16 + kg * 4 + j;
        if (row < M) C[(size_t)row * 256 + col] = vj;
        ps[j] += vj * vj;
      }
    }
#pragma unroll
    for (int j = 0; j < 4; j++) {
      float s = ps[j];
      s += __shfl_xor(s, 1);
      s += __shfl_xor(s, 2);
      s += __shfl_xor(s, 4);
      s += __shfl_xor(s, 8);
      if (m16 == 0) {
        int row = bm0 + wm + mi * 16 + kg * 4 + j;
        if (row < M) atomicAdd(&nrm_sq[row], s);
      }
    }
  }
}

// ---- in-place: nrm_sq[i] -> 1 / max(sqrt(nrm_sq[i]), EPS) ----
__global__ __launch_bounds__(256) void k_rnorm(float* __restrict__ sq, int M) {
  int i = blockIdx.x * blockDim.x + threadIdx.x;
  if (i < M) sq[i] = 1.0f / fmaxf(sqrtf(sq[i]), EPS_C);
}

// ---- pass A: bin edges into TB coarse buckets; packed entry = (src<<8)|(dst&255) ----
__global__ __launch_bounds__(1024) void k_bin(const int* __restrict__ src,
                                              const int* __restrict__ dst,
                                              int* __restrict__ cursor,
                                              int* __restrict__ binned) {
  __shared__ int hist[TB];
  __shared__ int base[TB];
  int tid = threadIdx.x;
  for (int i = tid; i < TB; i += 1024) hist[i] = 0;
  __syncthreads();
  int e0 = blockIdx.x * EPB;
  int myb[8], myrank[8], myp[8];
#pragma unroll
  for (int i = 0; i < 8; i++) {
    int e = e0 + i * 1024 + tid;
    myb[i] = -1;
    if (e < R_REL * E_EDGES) {
      int r = e / E_EDGES;
      int d = dst[e];
      int s = src[e];
      int b = r * NB + (d >> 8);
      myb[i]    = b;
      myp[i]    = (s << 8) | (d & 255);
      myrank[i] = atomicAdd(&hist[b], 1);
    }
  }
  __syncthreads();
  for (int i = tid; i < TB; i += 1024) {
    int c = hist[i];
    base[i] = c ? atomicAdd(&cursor[i], c) : 0;
  }
  __syncthreads();
#pragma unroll
  for (int i = 0; i < 8; i++) {
    if (myb[i] >= 0) {
      int pos = base[myb[i]] + myrank[i];
      if (pos < BCAP) binned[(size_t)myb[i] * BCAP + pos] = myp[i];
    }
  }
}

// ---- scan of TB bucket counts -> global bucket bases; also offsets[RN] ----
__global__ __launch_bounds__(1024) void k_bucket_scan(const int* __restrict__ cnt,
                                                      int* __restrict__ bbase,
                                                      int* __restrict__ offsets) {
  __shared__ int s[1024];
  int tid = threadIdx.x;
  int v = (tid < TB) ? cnt[tid] : 0;
  s[tid] = v;
  __syncthreads();
  for (int off = 1; off < 1024; off <<= 1) {
    int t2 = (tid >= off) ? s[tid - off] : 0;
    __syncthreads();
    s[tid] += t2;
    __syncthreads();
  }
  if (tid < TB) bbase[tid] = s[tid] - v;
  if (tid == TB - 1) offsets[RN] = s[tid];
}

// ---- pass B: per-bucket exact CSR (offsets + edge_src) ----
__global__ __launch_bounds__(256) void k_csr(const int* __restrict__ binned,
                                             const int* __restrict__ cnt_arr,
                                             const int* __restrict__ bbase,
                                             int* __restrict__ offsets,
                                             int* __restrict__ edge_src) {
  __shared__ int hist[256];
  __shared__ int excl[256];
  int b   = blockIdx.x;
  int tid = threadIdx.x;
  int cnt = cnt_arr[b]; if (cnt > BCAP) cnt = BCAP;
  int gbase = bbase[b];
  hist[tid] = 0;
  __syncthreads();
  const int* bp = binned + (size_t)b * BCAP;
  for (int i = tid; i < cnt; i += 256) atomicAdd(&hist[bp[i] & 255], 1);
  __syncthreads();
  int v = hist[tid];
  excl[tid] = v;
  __syncthreads();
  for (int off = 1; off < 256; off <<= 1) {
    int t2 = (tid >= off) ? excl[tid - off] : 0;
    __syncthreads();
    excl[tid] += t2;
    __syncthreads();
  }
  int ex = excl[tid] - v;                         // exclusive within bucket
  int r = b / NB, bloc = b % NB;
  int node = bloc * 256 + tid;
  if (node < N_NODES) offsets[r * N_NODES + node] = gbase + ex;
  hist[tid] = gbase + ex;                         // reuse as cursor
  __syncthreads();
  for (int i = tid; i < cnt; i += 256) {
    int p = bp[i];
    int pos = atomicAdd(&hist[p & 255], 1);
    edge_src[pos] = p >> 8;
  }
}

// ------ edge aggregation: one wave per (r, dst-node), software-pipelined ------
__global__ __launch_bounds__(256) void k_aggregate(int r,
                                                   const float* __restrict__ hr,
                                                   const float* __restrict__ ht,
                                                   const float* __restrict__ rn_hr,
                                                   const float* __restrict__ rn_ht,
                                                   const int* __restrict__ offsets,
                                                   const int* __restrict__ edge_src,
                                                   float* __restrict__ h,
                                                   float* __restrict__ ma) {
  int n    = (int)((blockIdx.x * (size_t)blockDim.x + threadIdx.x) >> 6);
  int lane = threadIdx.x & 63;
  if (n >= N_NODES) return;
  const float4 hd = *(const float4*)(ht + (size_t)n * DIM + lane * 4);
  float rd = rn_ht[n];
  int b     = offsets[r * N_NODES + n];
  int e_end = offsets[r * N_NODES + n + 1];
  float4 acc = {0.f, 0.f, 0.f, 0.f};
  float asum = 0.f;
  float4 hs_n = {0.f, 0.f, 0.f, 0.f};
  float rs_n = 0.f;
  if (b < e_end) {
    int sn = edge_src[b];
    hs_n = *(const float4*)(hr + (size_t)sn * DIM + lane * 4);
    rs_n = rn_hr[sn];
  }
  for (int e = b; e < e_end; e++) {
    float4 hs = hs_n;
    float rs = rs_n;
    if (e + 1 < e_end) {
      int sn2 = edge_src[e + 1];
      hs_n = *(const float4*)(hr + (size_t)sn2 * DIM + lane * 4);
      rs_n = rn_hr[sn2];
    }
    float num = hs.x * hd.x + hs.y * hd.y + hs.z * hd.z + hs.w * hd.w;
    for (int off = 32; off; off >>= 1) num += __shfl_xor(num, off);
    float s = num * rs * rd;
    acc.x += s * hs.x; acc.y += s * hs.y; acc.z += s * hs.z; acc.w += s * hs.w;
    asum += s;
  }
  *(float4*)(h + ((size_t)n * R_REL + r) * DIM + lane * 4) = acc;
  if (lane == 0) {
    float cnt = (float)(e_end - b);
    ma[n * R_REL + r] = asum / fmaxf(cnt, 1.0f);
  }
}

// ------- vulnerable nodes: mask + combine, 256 threads, float4-vectorized -------
__global__ __launch_bounds__(256) void k_vuln_combine(const float* __restrict__ h,
                                                      const int* __restrict__ cand,
                                                      const float* __restrict__ ma,
                                                      float* __restrict__ out) {
  __shared__ float red[8][4];
  __shared__ float dist2s[8];
  __shared__ float sm[1024];
  int n   = blockIdx.x;
  int tid = threadIdx.x;                       // owns elements tid*4 .. tid*4+3
  const float4 hv = *(const float4*)(h + (size_t)n * 1024 + tid * 4);
  float4 hc[8];
#pragma unroll
  for (int k = 0; k < 8; k++) {
    int c = cand[n * 8 + k];
    hc[k] = *(const float4*)(h + (size_t)c * 1024 + tid * 4);
  }
  float4 d2[8];
  int wid = tid >> 6, lane = tid & 63;
#pragma unroll
  for (int k = 0; k < 8; k++) {
    float4 df;
    df.x = hv.x - hc[k].x; df.y = hv.y - hc[k].y;
    df.z = hv.z - hc[k].z; df.w = hv.w - hc[k].w;
    d2[k].x = df.x * df.x; d2[k].y = df.y * df.y;
    d2[k].z = df.z * df.z; d2[k].w = df.w * df.w;
    float v = d2[k].x + d2[k].y + d2[k].z + d2[k].w;
    for (int off = 32; off; off >>= 1) v += __shfl_xor(v, off);
    if (lane == 0) red[k][wid] = v;
  }
  __syncthreads();
  if (tid < 32) {
    int k = tid >> 2, w2 = tid & 3;
    float v = red[k][w2];
    v += __shfl_xor(v, 1, 4);
    v += __shfl_xor(v, 2, 4);
    if (w2 == 0) dist2s[k] = v;
  }
  __syncthreads();
  float dk[8], mn = 1e30f;
#pragma unroll
  for (int k = 0; k < 8; k++) { dk[k] = sqrtf(dist2s[k]); mn = fminf(mn, dk[k]); }
  float se = 0.f, att[8];
#pragma unroll
  for (int k = 0; k < 8; k++) { att[k] = expf(mn - dk[k]); se += att[k]; }
  float inv = 1.f / se;
  float4 accv = {0.f, 0.f, 0.f, 0.f};
#pragma unroll
  for (int k = 0; k < 8; k++) {
    float a = att[k] * inv;
    accv.x += a * d2[k].x; accv.y += a * d2[k].y;
    accv.z += a * d2[k].z; accv.w += a * d2[k].w;
  }
  float m0 = ma[n * 4 + 0], m1 = ma[n * 4 + 1], m2 = ma[n * 4 + 2], m3 = ma[n * 4 + 3];
  float mx = fmaxf(fmaxf(m0, m1), fmaxf(m2, m3));
  float w0 = expf(m0 - mx), w1 = expf(m1 - mx), w2f = expf(m2 - mx), w3 = expf(m3 - mx);
  float winv = 1.f / (w0 + w1 + w2f + w3);
  float wr = (tid < 64) ? w0 : (tid < 128) ? w1 : (tid < 192) ? w2f : w3;
  float c = wr * winv;
  float4 o;
  o.x = c * hv.x * expf(-accv.x);
  o.y = c * hv.y * expf(-accv.y);
  o.z = c * hv.z * expf(-accv.z);
  o.w = c * hv.w * expf(-accv.w);
  *(float4*)&sm[tid * 4] = o;
  __syncthreads();
  if (tid < 256) {
    float v = sm[tid] + sm[256 + tid] + sm[512 + tid] + sm[768 + tid];
    out[(size_t)n * 256 + tid] = v;
  }
}

// ---------------- combine for non-vulnerable nodes ----------------
__global__ __launch_bounds__(256) void k_combine_rest(const float* __restrict__ h,
                                                      const float* __restrict__ ma,
                                                      float* __restrict__ out) {
  int n = NV_VUL + blockIdx.x;
  int d = threadIdx.x;
  float m0 = ma[n * 4 + 0], m1 = ma[n * 4 + 1], m2 = ma[n * 4 + 2], m3 = ma[n * 4 + 3];
  float mx = fmaxf(fmaxf(m0, m1), fmaxf(m2, m3));
  float w0 = expf(m0 - mx), w1 = expf(m1 - mx), w2 = expf(m2 - mx), w3 = expf(m3 - mx);
  float inv = 1.f / (w0 + w1 + w2 + w3);
  const float* hs = h + (size_t)n * 1024;
  float v = w0 * hs[d] + w1 * hs[256 + d] + w2 * hs[512 + d] + w3 * hs[768 + d];
  out[(size_t)n * 256 + d] = v * inv;
}

// ---------------- diagnostic fallback ----------------
__global__ void k_fallback(float* __restrict__ out, int out_size, float wsmb) {
  int i = blockIdx.x * blockDim.x + threadIdx.x;
  if (i < out_size) out[i] = (i == 0) ? wsmb : 0.f;
}

extern "C" void kernel_launch(void* const* d_in, const int* in_sizes, int n_in,
                              void* d_out, int out_size, void* d_ws, size_t ws_size,
                              hipStream_t stream) {
  const float* x   = (const float*)d_in[0];
  const float* We  = (const float*)d_in[1];
  const float* Wn  = (const float*)d_in[2];
  const float* bnb = (const float*)d_in[3];
  const int* src   = (const int*)d_in[4];
  const int* dst   = (const int*)d_in[5];
  const int* cand  = (const int*)d_in[6];
  float* out = (float*)d_out;

  char* ws = (char*)d_ws;
  size_t off = 0;
  auto alloc = [&](size_t bytes) -> void* {
    void* p = ws + off;
    off += (bytes + 255) & ~(size_t)255;
    return p;
  };
  float* ht          = (float*)alloc((size_t)N_NODES * DIM * 4);            // 51.2 MB
  float* h           = (float*)alloc((size_t)N_NODES * R_REL * DIM * 4);    // 204.8 MB
  float* ma          = (float*)alloc((size_t)N_NODES * R_REL * 4);
  float* nrm_ht_sq   = (float*)alloc((size_t)N_NODES * 4);                  // -> rnorm in place
  float* nrm_hr_sq   = (float*)alloc((size_t)N_NODES * 4);                  // -> rnorm in place
  int*   bucket_cnt  = (int*)alloc((size_t)TB * 4);                         // pass-A cursor == counts
  int*   bucket_base = (int*)alloc((size_t)TB * 4);
  int*   offsets     = (int*)alloc((size_t)(RN + 1) * 4);
  int*   edge_src    = (int*)alloc((size_t)R_REL * E_EDGES * 4);            // 8 MB
  short* Bthi        = (short*)alloc((size_t)5 * 65536 * 2);                // 0.66 MB
  short* Btlo        = (short*)alloc((size_t)5 * 65536 * 2);                // 0.66 MB
  size_t required = off;
  (void)in_sizes; (void)n_in;

  if (ws_size < required) {
    k_fallback<<<(out_size + 255) / 256, 256, 0, stream>>>(out, out_size,
                                                           (float)(ws_size >> 20));
    return;
  }

  float* hr = out;               // d_out doubles as the per-relation projection buffer
  int* binned = (int*)h;         // 16.06 MB bin staging aliases h (dead before aggregates)

  hipMemsetAsync(bucket_cnt, 0, (size_t)TB * 4, stream);
  hipMemsetAsync(nrm_ht_sq, 0, (size_t)N_NODES * 4, stream);

  k_convert_w<<<dim3(4, 4, 5), 256, 0, stream>>>(Wn, We, Bthi, Btlo);

  dim3 gemm_grid((N_NODES + GBM - 1) / GBM, DIM / GBN);

  // ht = x @ Wn + bn (split-bf16 MFMA), fused row sumsq -> reciprocal norm
  k_gemm_mfma<<<gemm_grid, 256, 0, stream>>>(x, Bthi, Btlo, bnb, ht, nrm_ht_sq, N_NODES);
  k_rnorm<<<(N_NODES + 255) / 256, 256, 0, stream>>>(nrm_ht_sq, N_NODES);

  // binned CSR build: bin -> bucket scan -> per-bucket CSR
  k_bin<<<(R_REL * E_EDGES + EPB - 1) / EPB, 1024, 0, stream>>>(src, dst, bucket_cnt, binned);
  k_bucket_scan<<<1, 1024, 0, stream>>>(bucket_cnt, bucket_base, offsets);
  k_csr<<<TB, 256, 0, stream>>>(binned, bucket_cnt, bucket_base, offsets, edge_src);

  // per relation: hr = x @ We[r] (MFMA); aggregate into h[:, r, :], ma[:, r]
  for (int r = 0; r < R_REL; r++) {
    hipMemsetAsync(nrm_hr_sq, 0, (size_t)N_NODES * 4, stream);
    k_gemm_mfma<<<gemm_grid, 256, 0, stream>>>(x, Bthi + (size_t)(1 + r) * 65536,
                                               Btlo + (size_t)(1 + r) * 65536,
                                               nullptr, hr, nrm_hr_sq, N_NODES);
    k_rnorm<<<(N_NODES + 255) / 256, 256, 0, stream>>>(nrm_hr_sq, N_NODES);
    k_aggregate<<<(N_NODES * 64 + 255) / 256, 256, 0, stream>>>(
        r, hr, ht, nrm_hr_sq, nrm_ht_sq, offsets, edge_src, h, ma);
  }

  // vulnerable nodes: mask + combine (reads pristine h, writes out rows [0, NV))
  k_vuln_combine<<<NV_VUL, 256, 0, stream>>>(h, cand, ma, out);

  // non-vulnerable nodes: combine (writes out rows [NV, N))
  k_combine_rest<<<N_NODES - NV_VUL, 256, 0, stream>>>(h, ma, out);
}

// Round 6
// 618.339 us; speedup vs baseline: 2.1381x; 1.1899x over previous
//
#include <hip/hip_runtime.h>

#define N_NODES 50000
#define DIM     256
#define R_REL   4
#define E_EDGES 500000
#define NV_VUL  10000
#define K_CAND  8
#define EPS_C   1e-8f
#define RN      (R_REL * N_NODES)            // 200000
#define NB      196                          // buckets per relation (256 nodes each)
#define TB      (R_REL * NB)                 // 784 total buckets
#define BCAP    5120                         // capacity per bucket (mean 2551)
#define EPB     8192                         // edges per k_bin block

typedef short bf16x8 __attribute__((ext_vector_type(8)));
typedef float f32x4  __attribute__((ext_vector_type(4)));

__device__ __forceinline__ unsigned short f2bf_rne(float f) {
  unsigned u = __builtin_bit_cast(unsigned, f);
  unsigned r = (u + 0x7FFFu + ((u >> 16) & 1u)) >> 16;
  return (unsigned short)r;
}
__device__ __forceinline__ float bf2f(unsigned short h) {
  unsigned u = ((unsigned)h) << 16;
  return __builtin_bit_cast(float, u);
}
__device__ __forceinline__ void cvt8(float4 a, float4 b, bf16x8* h, bf16x8* l) {
  float f[8] = {a.x, a.y, a.z, a.w, b.x, b.y, b.z, b.w};
  bf16x8 hh, ll;
#pragma unroll
  for (int i = 0; i < 8; i++) {
    unsigned short hv = f2bf_rne(f[i]);
    hh[i] = (short)hv;
    ll[i] = (short)f2bf_rne(f[i] - bf2f(hv));
  }
  *h = hh; *l = ll;
}
__device__ __forceinline__ bf16x8 cvt8hi(float4 a, float4 b) {
  float f[8] = {a.x, a.y, a.z, a.w, b.x, b.y, b.z, b.w};
  bf16x8 hh;
#pragma unroll
  for (int i = 0; i < 8; i++) hh[i] = (short)f2bf_rne(f[i]);
  return hh;
}

// ---- weight prep: Bt_hi[w][n][k] for all w; Bt_lo only for w=0 (Wn) ----
__global__ __launch_bounds__(256) void k_convert_w(const float* __restrict__ Wn,
                                                   const float* __restrict__ We,
                                                   short* __restrict__ Bthi,
                                                   short* __restrict__ Btlo) {
  __shared__ float tile[64][65];
  int w  = blockIdx.z;                    // 0 = Wn, 1..4 = We[w-1]
  int k0 = blockIdx.x * 64, n0 = blockIdx.y * 64;
  const float* W = (w == 0) ? Wn : We + (size_t)(w - 1) * 65536;
  int tx = threadIdx.x & 63, ty = threadIdx.x >> 6;
  for (int i = ty; i < 64; i += 4)
    tile[i][tx] = W[(size_t)(k0 + i) * 256 + n0 + tx];
  __syncthreads();
  for (int i = ty; i < 64; i += 4) {
    float f = tile[tx][i];                // = W[k0+tx][n0+i]
    unsigned short h = f2bf_rne(f);
    size_t o = (size_t)w * 65536 + (size_t)(n0 + i) * 256 + k0 + tx;
    Bthi[o] = (short)h;
    if (w == 0) Btlo[(size_t)(n0 + i) * 256 + k0 + tx] = (short)f2bf_rne(f - bf2f(h));
  }
}

#define GBM 128
#define GBN 128
#define GBK 32
// ---- 3-pass split-bf16 MFMA GEMM (fp32 out + bias + fused sumsq) — used for ht ----
__global__ __launch_bounds__(256) void k_gemm_mfma(const float* __restrict__ A,
                                                   const short* __restrict__ Bthi,
                                                   const short* __restrict__ Btlo,
                                                   const float* __restrict__ bias,
                                                   float* __restrict__ C,
                                                   float* __restrict__ nrm_sq,
                                                   int M) {
  __shared__ short Ahi_s[128][GBK + 8];
  __shared__ short Alo_s[128][GBK + 8];
  __shared__ short Bhi_s[128][GBK + 8];
  __shared__ short Blo_s[128][GBK + 8];
  const int t    = threadIdx.x;
  const int bm0  = blockIdx.x * GBM;
  const int bn0  = blockIdx.y * GBN;
  const int wave = t >> 6, lane = t & 63;
  const int wm   = (wave >> 1) * 64, wn = (wave & 1) * 64;
  const int m16  = lane & 15, kg = lane >> 4;

  f32x4 acc[4][4] = {};

  const int srow  = t >> 1;
  const int shalf = t & 1;
  int agrow = bm0 + srow; if (agrow >= M) agrow = M - 1;
  const float* aptr   = A    + (size_t)agrow * 256 + shalf * 16;
  const short* bhiptr = Bthi + (size_t)(bn0 + srow) * 256 + shalf * 16;
  const short* bloptr = Btlo + (size_t)(bn0 + srow) * 256 + shalf * 16;

  for (int k0 = 0; k0 < DIM; k0 += GBK) {
    float4 av0 = *(const float4*)(aptr + k0);
    float4 av1 = *(const float4*)(aptr + k0 + 4);
    float4 av2 = *(const float4*)(aptr + k0 + 8);
    float4 av3 = *(const float4*)(aptr + k0 + 12);
    bf16x8 h0, l0, h1, l1;
    cvt8(av0, av1, &h0, &l0);
    cvt8(av2, av3, &h1, &l1);
    *(bf16x8*)&Ahi_s[srow][shalf * 16 + 0] = h0;
    *(bf16x8*)&Ahi_s[srow][shalf * 16 + 8] = h1;
    *(bf16x8*)&Alo_s[srow][shalf * 16 + 0] = l0;
    *(bf16x8*)&Alo_s[srow][shalf * 16 + 8] = l1;
    *(bf16x8*)&Bhi_s[srow][shalf * 16 + 0] = *(const bf16x8*)(bhiptr + k0);
    *(bf16x8*)&Bhi_s[srow][shalf * 16 + 8] = *(const bf16x8*)(bhiptr + k0 + 8);
    *(bf16x8*)&Blo_s[srow][shalf * 16 + 0] = *(const bf16x8*)(bloptr + k0);
    *(bf16x8*)&Blo_s[srow][shalf * 16 + 8] = *(const bf16x8*)(bloptr + k0 + 8);
    __syncthreads();

    bf16x8 ah[4], al[4], bh[4], bl[4];
#pragma unroll
    for (int i = 0; i < 4; i++) {
      ah[i] = *(const bf16x8*)&Ahi_s[wm + i * 16 + m16][kg * 8];
      al[i] = *(const bf16x8*)&Alo_s[wm + i * 16 + m16][kg * 8];
      bh[i] = *(const bf16x8*)&Bhi_s[wn + i * 16 + m16][kg * 8];
      bl[i] = *(const bf16x8*)&Blo_s[wn + i * 16 + m16][kg * 8];
    }
#pragma unroll
    for (int mi = 0; mi < 4; mi++)
#pragma unroll
      for (int ni = 0; ni < 4; ni++) {
        acc[mi][ni] = __builtin_amdgcn_mfma_f32_16x16x32_bf16(ah[mi], bh[ni], acc[mi][ni], 0, 0, 0);
        acc[mi][ni] = __builtin_amdgcn_mfma_f32_16x16x32_bf16(ah[mi], bl[ni], acc[mi][ni], 0, 0, 0);
        acc[mi][ni] = __builtin_amdgcn_mfma_f32_16x16x32_bf16(al[mi], bh[ni], acc[mi][ni], 0, 0, 0);
      }
    __syncthreads();
  }

#pragma unroll
  for (int mi = 0; mi < 4; mi++) {
    float ps[4] = {0.f, 0.f, 0.f, 0.f};
#pragma unroll
    for (int ni = 0; ni < 4; ni++) {
      int col = bn0 + wn + ni * 16 + m16;
      float bb = bias ? bias[col] : 0.f;
      f32x4 v = acc[mi][ni];
#pragma unroll
      for (int j = 0; j < 4; j++) {
        float vj = v[j] + bb;
        int row = bm0 + wm + mi * 16 + kg * 4 + j;
        if (row < M) C[(size_t)row * 256 + col] = vj;
        ps[j] += vj * vj;
      }
    }
#pragma unroll
    for (int j = 0; j < 4; j++) {
      float s = ps[j];
      s += __shfl_xor(s, 1);
      s += __shfl_xor(s, 2);
      s += __shfl_xor(s, 4);
      s += __shfl_xor(s, 8);
      if (m16 == 0) {
        int row = bm0 + wm + mi * 16 + kg * 4 + j;
        if (row < M) atomicAdd(&nrm_sq[row], s);
      }
    }
  }
}

// ---- single-pass bf16 MFMA GEMM, bf16 out + fused sumsq — used for hr ----
__global__ __launch_bounds__(256) void k_gemm_bf16(const float* __restrict__ A,
                                                   const short* __restrict__ Bthi,
                                                   unsigned short* __restrict__ C16,
                                                   float* __restrict__ nrm_sq,
                                                   int M) {
  __shared__ short Ahi_s[128][GBK + 8];
  __shared__ short Bhi_s[128][GBK + 8];
  const int t    = threadIdx.x;
  const int bm0  = blockIdx.x * GBM;
  const int bn0  = blockIdx.y * GBN;
  const int wave = t >> 6, lane = t & 63;
  const int wm   = (wave >> 1) * 64, wn = (wave & 1) * 64;
  const int m16  = lane & 15, kg = lane >> 4;

  f32x4 acc[4][4] = {};

  const int srow  = t >> 1;
  const int shalf = t & 1;
  int agrow = bm0 + srow; if (agrow >= M) agrow = M - 1;
  const float* aptr   = A    + (size_t)agrow * 256 + shalf * 16;
  const short* bhiptr = Bthi + (size_t)(bn0 + srow) * 256 + shalf * 16;

  for (int k0 = 0; k0 < DIM; k0 += GBK) {
    float4 av0 = *(const float4*)(aptr + k0);
    float4 av1 = *(const float4*)(aptr + k0 + 4);
    float4 av2 = *(const float4*)(aptr + k0 + 8);
    float4 av3 = *(const float4*)(aptr + k0 + 12);
    *(bf16x8*)&Ahi_s[srow][shalf * 16 + 0] = cvt8hi(av0, av1);
    *(bf16x8*)&Ahi_s[srow][shalf * 16 + 8] = cvt8hi(av2, av3);
    *(bf16x8*)&Bhi_s[srow][shalf * 16 + 0] = *(const bf16x8*)(bhiptr + k0);
    *(bf16x8*)&Bhi_s[srow][shalf * 16 + 8] = *(const bf16x8*)(bhiptr + k0 + 8);
    __syncthreads();

    bf16x8 ah[4], bh[4];
#pragma unroll
    for (int i = 0; i < 4; i++) {
      ah[i] = *(const bf16x8*)&Ahi_s[wm + i * 16 + m16][kg * 8];
      bh[i] = *(const bf16x8*)&Bhi_s[wn + i * 16 + m16][kg * 8];
    }
#pragma unroll
    for (int mi = 0; mi < 4; mi++)
#pragma unroll
      for (int ni = 0; ni < 4; ni++)
        acc[mi][ni] = __builtin_amdgcn_mfma_f32_16x16x32_bf16(ah[mi], bh[ni], acc[mi][ni], 0, 0, 0);
    __syncthreads();
  }

#pragma unroll
  for (int mi = 0; mi < 4; mi++) {
    float ps[4] = {0.f, 0.f, 0.f, 0.f};
#pragma unroll
    for (int ni = 0; ni < 4; ni++) {
      int col = bn0 + wn + ni * 16 + m16;
      f32x4 v = acc[mi][ni];
#pragma unroll
      for (int j = 0; j < 4; j++) {
        float vj = v[j];
        int row = bm0 + wm + mi * 16 + kg * 4 + j;
        if (row < M) C16[(size_t)row * 256 + col] = f2bf_rne(vj);
        ps[j] += vj * vj;
      }
    }
#pragma unroll
    for (int j = 0; j < 4; j++) {
      float s = ps[j];
      s += __shfl_xor(s, 1);
      s += __shfl_xor(s, 2);
      s += __shfl_xor(s, 4);
      s += __shfl_xor(s, 8);
      if (m16 == 0) {
        int row = bm0 + wm + mi * 16 + kg * 4 + j;
        if (row < M) atomicAdd(&nrm_sq[row], s);
      }
    }
  }
}

// ---- pass A: bin edges into TB coarse buckets; packed entry = (src<<8)|(dst&255) ----
__global__ __launch_bounds__(1024) void k_bin(const int* __restrict__ src,
                                              const int* __restrict__ dst,
                                              int* __restrict__ cursor,
                                              int* __restrict__ binned) {
  __shared__ int hist[TB];
  __shared__ int base[TB];
  int tid = threadIdx.x;
  for (int i = tid; i < TB; i += 1024) hist[i] = 0;
  __syncthreads();
  int e0 = blockIdx.x * EPB;
  int myb[8], myrank[8], myp[8];
#pragma unroll
  for (int i = 0; i < 8; i++) {
    int e = e0 + i * 1024 + tid;
    myb[i] = -1;
    if (e < R_REL * E_EDGES) {
      int r = e / E_EDGES;
      int d = dst[e];
      int s = src[e];
      int b = r * NB + (d >> 8);
      myb[i]    = b;
      myp[i]    = (s << 8) | (d & 255);
      myrank[i] = atomicAdd(&hist[b], 1);
    }
  }
  __syncthreads();
  for (int i = tid; i < TB; i += 1024) {
    int c = hist[i];
    base[i] = c ? atomicAdd(&cursor[i], c) : 0;
  }
  __syncthreads();
#pragma unroll
  for (int i = 0; i < 8; i++) {
    if (myb[i] >= 0) {
      int pos = base[myb[i]] + myrank[i];
      if (pos < BCAP) binned[(size_t)myb[i] * BCAP + pos] = myp[i];
    }
  }
}

// ---- scan of TB bucket counts -> global bucket bases; also offsets[RN] ----
__global__ __launch_bounds__(1024) void k_bucket_scan(const int* __restrict__ cnt,
                                                      int* __restrict__ bbase,
                                                      int* __restrict__ offsets) {
  __shared__ int s[1024];
  int tid = threadIdx.x;
  int v = (tid < TB) ? cnt[tid] : 0;
  s[tid] = v;
  __syncthreads();
  for (int off = 1; off < 1024; off <<= 1) {
    int t2 = (tid >= off) ? s[tid - off] : 0;
    __syncthreads();
    s[tid] += t2;
    __syncthreads();
  }
  if (tid < TB) bbase[tid] = s[tid] - v;
  if (tid == TB - 1) offsets[RN] = s[tid];
}

// ---- pass B: per-bucket exact CSR (offsets + edge_src) ----
__global__ __launch_bounds__(256) void k_csr(const int* __restrict__ binned,
                                             const int* __restrict__ cnt_arr,
                                             const int* __restrict__ bbase,
                                             int* __restrict__ offsets,
                                             int* __restrict__ edge_src) {
  __shared__ int hist[256];
  __shared__ int excl[256];
  int b   = blockIdx.x;
  int tid = threadIdx.x;
  int cnt = cnt_arr[b]; if (cnt > BCAP) cnt = BCAP;
  int gbase = bbase[b];
  hist[tid] = 0;
  __syncthreads();
  const int* bp = binned + (size_t)b * BCAP;
  for (int i = tid; i < cnt; i += 256) atomicAdd(&hist[bp[i] & 255], 1);
  __syncthreads();
  int v = hist[tid];
  excl[tid] = v;
  __syncthreads();
  for (int off = 1; off < 256; off <<= 1) {
    int t2 = (tid >= off) ? excl[tid - off] : 0;
    __syncthreads();
    excl[tid] += t2;
    __syncthreads();
  }
  int ex = excl[tid] - v;                         // exclusive within bucket
  int r = b / NB, bloc = b % NB;
  int node = bloc * 256 + tid;
  if (node < N_NODES) offsets[r * N_NODES + node] = gbase + ex;
  hist[tid] = gbase + ex;                         // reuse as cursor
  __syncthreads();
  for (int i = tid; i < cnt; i += 256) {
    int p = bp[i];
    int pos = atomicAdd(&hist[p & 255], 1);
    edge_src[pos] = p >> 8;
  }
}

// ------ edge aggregation: one wave per (r, dst-node), bf16 gather, pipelined ------
__global__ __launch_bounds__(256) void k_aggregate(int r,
                                                   const unsigned short* __restrict__ hr16,
                                                   const float* __restrict__ ht,
                                                   const float* __restrict__ nsq_hr,
                                                   const float* __restrict__ nsq_ht,
                                                   const int* __restrict__ offsets,
                                                   const int* __restrict__ edge_src,
                                                   float* __restrict__ h,
                                                   float* __restrict__ ma,
                                                   unsigned short* __restrict__ stash) {
  int n    = (int)((blockIdx.x * (size_t)blockDim.x + threadIdx.x) >> 6);
  int lane = threadIdx.x & 63;
  if (n >= N_NODES) return;
  const float4 hd = *(const float4*)(ht + (size_t)n * DIM + lane * 4);
  float rd = fminf(rsqrtf(nsq_ht[n]), 1e8f);
  int b     = offsets[r * N_NODES + n];
  int e_end = offsets[r * N_NODES + n + 1];
  float4 acc = {0.f, 0.f, 0.f, 0.f};
  float asum = 0.f;
  ushort4 u_n = {0, 0, 0, 0};
  float q_n = 1.f;
  if (b < e_end) {
    int sn = edge_src[b];
    u_n = *(const ushort4*)(hr16 + (size_t)sn * DIM + lane * 4);
    q_n = nsq_hr[sn];
  }
  for (int e = b; e < e_end; e++) {
    ushort4 u = u_n;
    float q = q_n;
    if (e + 1 < e_end) {
      int sn2 = edge_src[e + 1];
      u_n = *(const ushort4*)(hr16 + (size_t)sn2 * DIM + lane * 4);
      q_n = nsq_hr[sn2];
    }
    float4 hs;
    hs.x = bf2f(u.x); hs.y = bf2f(u.y); hs.z = bf2f(u.z); hs.w = bf2f(u.w);
    float num = hs.x * hd.x + hs.y * hd.y + hs.z * hd.z + hs.w * hd.w;
    for (int off = 32; off; off >>= 1) num += __shfl_xor(num, off);
    float rs = fminf(rsqrtf(q), 1e8f);
    float s = num * rs * rd;
    acc.x += s * hs.x; acc.y += s * hs.y; acc.z += s * hs.z; acc.w += s * hs.w;
    asum += s;
  }
  *(float4*)(h + ((size_t)n * R_REL + r) * DIM + lane * 4) = acc;
  if (n < NV_VUL) {
    ushort4 o;
    o.x = f2bf_rne(acc.x); o.y = f2bf_rne(acc.y);
    o.z = f2bf_rne(acc.z); o.w = f2bf_rne(acc.w);
    *(ushort4*)(stash + ((size_t)n * R_REL + r) * DIM + lane * 4) = o;
  }
  if (lane == 0) {
    float cnt = (float)(e_end - b);
    ma[n * R_REL + r] = asum / fmaxf(cnt, 1.0f);
  }
}

// ------- vulnerable nodes: mask + combine; candidate distances from bf16 stash -------
__global__ __launch_bounds__(256) void k_vuln_combine(const float* __restrict__ h,
                                                      const unsigned short* __restrict__ stash,
                                                      const int* __restrict__ cand,
                                                      const float* __restrict__ ma,
                                                      float* __restrict__ out) {
  __shared__ float red[8][4];
  __shared__ float dist2s[8];
  __shared__ float sm[1024];
  int n   = blockIdx.x;
  int tid = threadIdx.x;                       // owns elements tid*4 .. tid*4+3
  const float4 hv = *(const float4*)(h + (size_t)n * 1024 + tid * 4);
  ushort4 hb = *(const ushort4*)(stash + (size_t)n * 1024 + tid * 4);
  float4 hvb;
  hvb.x = bf2f(hb.x); hvb.y = bf2f(hb.y); hvb.z = bf2f(hb.z); hvb.w = bf2f(hb.w);
  float4 d2[8];
  int wid = tid >> 6, lane = tid & 63;
#pragma unroll
  for (int k = 0; k < 8; k++) {
    int c = cand[n * 8 + k];
    ushort4 cb = *(const ushort4*)(stash + (size_t)c * 1024 + tid * 4);
    float4 df;
    df.x = hvb.x - bf2f(cb.x); df.y = hvb.y - bf2f(cb.y);
    df.z = hvb.z - bf2f(cb.z); df.w = hvb.w - bf2f(cb.w);
    d2[k].x = df.x * df.x; d2[k].y = df.y * df.y;
    d2[k].z = df.z * df.z; d2[k].w = df.w * df.w;
    float v = d2[k].x + d2[k].y + d2[k].z + d2[k].w;
    for (int off = 32; off; off >>= 1) v += __shfl_xor(v, off);
    if (lane == 0) red[k][wid] = v;
  }
  __syncthreads();
  if (tid < 32) {
    int k = tid >> 2, w2 = tid & 3;
    float v = red[k][w2];
    v += __shfl_xor(v, 1, 4);
    v += __shfl_xor(v, 2, 4);
    if (w2 == 0) dist2s[k] = v;
  }
  __syncthreads();
  float dk[8], mn = 1e30f;
#pragma unroll
  for (int k = 0; k < 8; k++) { dk[k] = sqrtf(dist2s[k]); mn = fminf(mn, dk[k]); }
  float se = 0.f, att[8];
#pragma unroll
  for (int k = 0; k < 8; k++) { att[k] = expf(mn - dk[k]); se += att[k]; }
  float inv = 1.f / se;
  float4 accv = {0.f, 0.f, 0.f, 0.f};
#pragma unroll
  for (int k = 0; k < 8; k++) {
    float a = att[k] * inv;
    accv.x += a * d2[k].x; accv.y += a * d2[k].y;
    accv.z += a * d2[k].z; accv.w += a * d2[k].w;
  }
  float m0 = ma[n * 4 + 0], m1 = ma[n * 4 + 1], m2 = ma[n * 4 + 2], m3 = ma[n * 4 + 3];
  float mx = fmaxf(fmaxf(m0, m1), fmaxf(m2, m3));
  float w0 = expf(m0 - mx), w1 = expf(m1 - mx), w2f = expf(m2 - mx), w3 = expf(m3 - mx);
  float winv = 1.f / (w0 + w1 + w2f + w3);
  float wr = (tid < 64) ? w0 : (tid < 128) ? w1 : (tid < 192) ? w2f : w3;
  float c = wr * winv;
  float4 o;
  o.x = c * hv.x * expf(-accv.x);
  o.y = c * hv.y * expf(-accv.y);
  o.z = c * hv.z * expf(-accv.z);
  o.w = c * hv.w * expf(-accv.w);
  *(float4*)&sm[tid * 4] = o;
  __syncthreads();
  if (tid < 256) {
    float v = sm[tid] + sm[256 + tid] + sm[512 + tid] + sm[768 + tid];
    out[(size_t)n * 256 + tid] = v;
  }
}

// ---------------- combine for non-vulnerable nodes ----------------
__global__ __launch_bounds__(256) void k_combine_rest(const float* __restrict__ h,
                                                      const float* __restrict__ ma,
                                                      float* __restrict__ out) {
  int n = NV_VUL + blockIdx.x;
  int d = threadIdx.x;
  float m0 = ma[n * 4 + 0], m1 = ma[n * 4 + 1], m2 = ma[n * 4 + 2], m3 = ma[n * 4 + 3];
  float mx = fmaxf(fmaxf(m0, m1), fmaxf(m2, m3));
  float w0 = expf(m0 - mx), w1 = expf(m1 - mx), w2 = expf(m2 - mx), w3 = expf(m3 - mx);
  float inv = 1.f / (w0 + w1 + w2 + w3);
  const float* hs = h + (size_t)n * 1024;
  float v = w0 * hs[d] + w1 * hs[256 + d] + w2 * hs[512 + d] + w3 * hs[768 + d];
  out[(size_t)n * 256 + d] = v * inv;
}

// ---------------- diagnostic fallback ----------------
__global__ void k_fallback(float* __restrict__ out, int out_size, float wsmb) {
  int i = blockIdx.x * blockDim.x + threadIdx.x;
  if (i < out_size) out[i] = (i == 0) ? wsmb : 0.f;
}

extern "C" void kernel_launch(void* const* d_in, const int* in_sizes, int n_in,
                              void* d_out, int out_size, void* d_ws, size_t ws_size,
                              hipStream_t stream) {
  const float* x   = (const float*)d_in[0];
  const float* We  = (const float*)d_in[1];
  const float* Wn  = (const float*)d_in[2];
  const float* bnb = (const float*)d_in[3];
  const int* src   = (const int*)d_in[4];
  const int* dst   = (const int*)d_in[5];
  const int* cand  = (const int*)d_in[6];
  float* out = (float*)d_out;

  char* ws = (char*)d_ws;
  size_t off = 0;
  auto alloc = [&](size_t bytes) -> void* {
    void* p = ws + off;
    off += (bytes + 255) & ~(size_t)255;
    return p;
  };
  float* ht          = (float*)alloc((size_t)N_NODES * DIM * 4);            // 51.2 MB
  float* h           = (float*)alloc((size_t)N_NODES * R_REL * DIM * 4);    // 204.8 MB
  float* ma          = (float*)alloc((size_t)N_NODES * R_REL * 4);
  float* nsq         = (float*)alloc((size_t)5 * N_NODES * 4);              // [0]=ht, [1+r]=hr
  int*   bucket_cnt  = (int*)alloc((size_t)TB * 4);
  int*   bucket_base = (int*)alloc((size_t)TB * 4);
  int*   offsets     = (int*)alloc((size_t)(RN + 1) * 4);
  int*   edge_src    = (int*)alloc((size_t)R_REL * E_EDGES * 4);            // 8 MB
  short* Bthi        = (short*)alloc((size_t)5 * 65536 * 2);                // 0.66 MB
  short* Btlo        = (short*)alloc((size_t)65536 * 2);                    // 0.13 MB (Wn only)
  size_t required = off;
  (void)in_sizes; (void)n_in;

  if (ws_size < required) {
    k_fallback<<<(out_size + 255) / 256, 256, 0, stream>>>(out, out_size,
                                                           (float)(ws_size >> 20));
    return;
  }

  // d_out aliases: [0, 25.6MB) = bf16 hr; [25.6MB, 46.6MB) = bf16 stash of h[:NV].
  // Both are dead before k_vuln_combine/k_combine_rest write out (stream-ordered).
  unsigned short* hr16  = (unsigned short*)out;
  unsigned short* stash = hr16 + (size_t)N_NODES * DIM;
  int* binned = (int*)h;         // 16.06 MB bin staging aliases h (dead before aggregates)

  hipMemsetAsync(bucket_cnt, 0, (size_t)TB * 4, stream);
  hipMemsetAsync(nsq, 0, (size_t)5 * N_NODES * 4, stream);

  k_convert_w<<<dim3(4, 4, 5), 256, 0, stream>>>(Wn, We, Bthi, Btlo);

  dim3 gemm_grid((N_NODES + GBM - 1) / GBM, DIM / GBN);

  // ht = x @ Wn + bn (3-pass split-bf16 MFMA, fp32 out), fused sumsq
  k_gemm_mfma<<<gemm_grid, 256, 0, stream>>>(x, Bthi, Btlo, bnb, ht, nsq, N_NODES);

  // binned CSR build: bin -> bucket scan -> per-bucket CSR
  k_bin<<<(R_REL * E_EDGES + EPB - 1) / EPB, 1024, 0, stream>>>(src, dst, bucket_cnt, binned);
  k_bucket_scan<<<1, 1024, 0, stream>>>(bucket_cnt, bucket_base, offsets);
  k_csr<<<TB, 256, 0, stream>>>(binned, bucket_cnt, bucket_base, offsets, edge_src);

  // per relation: hr16 = bf16(x @ We[r]) (1-pass MFMA); aggregate into h[:, r, :], ma[:, r]
  for (int r = 0; r < R_REL; r++) {
    k_gemm_bf16<<<gemm_grid, 256, 0, stream>>>(x, Bthi + (size_t)(1 + r) * 65536,
                                               hr16, nsq + (size_t)(1 + r) * N_NODES, N_NODES);
    k_aggregate<<<(N_NODES * 64 + 255) / 256, 256, 0, stream>>>(
        r, hr16, ht, nsq + (size_t)(1 + r) * N_NODES, nsq, offsets, edge_src, h, ma, stash);
  }

  // vulnerable nodes: mask + combine (reads h + stash, writes out rows [0, NV))
  k_vuln_combine<<<NV_VUL, 256, 0, stream>>>(h, stash, cand, ma, out);

  // non-vulnerable nodes: combine (writes out rows [NV, N))
  k_combine_rest<<<N_NODES - NV_VUL, 256, 0, stream>>>(h, ma, out);
}

// Round 7
// 485.328 us; speedup vs baseline: 2.7241x; 1.2741x over previous
//
#include <hip/hip_runtime.h>

#define N_NODES 50000
#define DIM     256
#define R_REL   4
#define E_EDGES 500000
#define NV_VUL  10000
#define K_CAND  8
#define EPS_C   1e-8f
#define RN      (R_REL * N_NODES)            // 200000
#define NB      196                          // buckets per relation (256 nodes each)
#define TB      (R_REL * NB)                 // 784 total buckets
#define BCAP    5120                         // capacity per bucket (mean 2551)
#define EPB     8192                         // edges per k_bin block

typedef short bf16x8 __attribute__((ext_vector_type(8)));
typedef float f32x4  __attribute__((ext_vector_type(4)));
typedef unsigned short us8 __attribute__((ext_vector_type(8)));

__device__ __forceinline__ unsigned short f2bf_rne(float f) {
  unsigned u = __builtin_bit_cast(unsigned, f);
  unsigned r = (u + 0x7FFFu + ((u >> 16) & 1u)) >> 16;
  return (unsigned short)r;
}
__device__ __forceinline__ float bf2f(unsigned short h) {
  unsigned u = ((unsigned)h) << 16;
  return __builtin_bit_cast(float, u);
}
__device__ __forceinline__ void cvt8(float4 a, float4 b, bf16x8* h, bf16x8* l) {
  float f[8] = {a.x, a.y, a.z, a.w, b.x, b.y, b.z, b.w};
  bf16x8 hh, ll;
#pragma unroll
  for (int i = 0; i < 8; i++) {
    unsigned short hv = f2bf_rne(f[i]);
    hh[i] = (short)hv;
    ll[i] = (short)f2bf_rne(f[i] - bf2f(hv));
  }
  *h = hh; *l = ll;
}
__device__ __forceinline__ bf16x8 cvt8hi(float4 a, float4 b) {
  float f[8] = {a.x, a.y, a.z, a.w, b.x, b.y, b.z, b.w};
  bf16x8 hh;
#pragma unroll
  for (int i = 0; i < 8; i++) hh[i] = (short)f2bf_rne(f[i]);
  return hh;
}

// ---- weight prep: Bt_hi[w][n][k] for all w; Bt_lo only for w=0 (Wn) ----
__global__ __launch_bounds__(256) void k_convert_w(const float* __restrict__ Wn,
                                                   const float* __restrict__ We,
                                                   short* __restrict__ Bthi,
                                                   short* __restrict__ Btlo) {
  __shared__ float tile[64][65];
  int w  = blockIdx.z;                    // 0 = Wn, 1..4 = We[w-1]
  int k0 = blockIdx.x * 64, n0 = blockIdx.y * 64;
  const float* W = (w == 0) ? Wn : We + (size_t)(w - 1) * 65536;
  int tx = threadIdx.x & 63, ty = threadIdx.x >> 6;
  for (int i = ty; i < 64; i += 4)
    tile[i][tx] = W[(size_t)(k0 + i) * 256 + n0 + tx];
  __syncthreads();
  for (int i = ty; i < 64; i += 4) {
    float f = tile[tx][i];                // = W[k0+tx][n0+i]
    unsigned short h = f2bf_rne(f);
    size_t o = (size_t)w * 65536 + (size_t)(n0 + i) * 256 + k0 + tx;
    Bthi[o] = (short)h;
    if (w == 0) Btlo[(size_t)(n0 + i) * 256 + k0 + tx] = (short)f2bf_rne(f - bf2f(h));
  }
}

#define GBM 128
#define GBN 128
#define GBK 32
// ---- 3-pass split-bf16 MFMA GEMM (fp32 out + bias + fused sumsq) — used for ht ----
__global__ __launch_bounds__(256) void k_gemm_mfma(const float* __restrict__ A,
                                                   const short* __restrict__ Bthi,
                                                   const short* __restrict__ Btlo,
                                                   const float* __restrict__ bias,
                                                   float* __restrict__ C,
                                                   float* __restrict__ nrm_sq,
                                                   int M) {
  __shared__ short Ahi_s[128][GBK + 8];
  __shared__ short Alo_s[128][GBK + 8];
  __shared__ short Bhi_s[128][GBK + 8];
  __shared__ short Blo_s[128][GBK + 8];
  const int t    = threadIdx.x;
  const int bm0  = blockIdx.x * GBM;
  const int bn0  = blockIdx.y * GBN;
  const int wave = t >> 6, lane = t & 63;
  const int wm   = (wave >> 1) * 64, wn = (wave & 1) * 64;
  const int m16  = lane & 15, kg = lane >> 4;

  f32x4 acc[4][4] = {};

  const int srow  = t >> 1;
  const int shalf = t & 1;
  int agrow = bm0 + srow; if (agrow >= M) agrow = M - 1;
  const float* aptr   = A    + (size_t)agrow * 256 + shalf * 16;
  const short* bhiptr = Bthi + (size_t)(bn0 + srow) * 256 + shalf * 16;
  const short* bloptr = Btlo + (size_t)(bn0 + srow) * 256 + shalf * 16;

  for (int k0 = 0; k0 < DIM; k0 += GBK) {
    float4 av0 = *(const float4*)(aptr + k0);
    float4 av1 = *(const float4*)(aptr + k0 + 4);
    float4 av2 = *(const float4*)(aptr + k0 + 8);
    float4 av3 = *(const float4*)(aptr + k0 + 12);
    bf16x8 h0, l0, h1, l1;
    cvt8(av0, av1, &h0, &l0);
    cvt8(av2, av3, &h1, &l1);
    *(bf16x8*)&Ahi_s[srow][shalf * 16 + 0] = h0;
    *(bf16x8*)&Ahi_s[srow][shalf * 16 + 8] = h1;
    *(bf16x8*)&Alo_s[srow][shalf * 16 + 0] = l0;
    *(bf16x8*)&Alo_s[srow][shalf * 16 + 8] = l1;
    *(bf16x8*)&Bhi_s[srow][shalf * 16 + 0] = *(const bf16x8*)(bhiptr + k0);
    *(bf16x8*)&Bhi_s[srow][shalf * 16 + 8] = *(const bf16x8*)(bhiptr + k0 + 8);
    *(bf16x8*)&Blo_s[srow][shalf * 16 + 0] = *(const bf16x8*)(bloptr + k0);
    *(bf16x8*)&Blo_s[srow][shalf * 16 + 8] = *(const bf16x8*)(bloptr + k0 + 8);
    __syncthreads();

    bf16x8 ah[4], al[4], bh[4], bl[4];
#pragma unroll
    for (int i = 0; i < 4; i++) {
      ah[i] = *(const bf16x8*)&Ahi_s[wm + i * 16 + m16][kg * 8];
      al[i] = *(const bf16x8*)&Alo_s[wm + i * 16 + m16][kg * 8];
      bh[i] = *(const bf16x8*)&Bhi_s[wn + i * 16 + m16][kg * 8];
      bl[i] = *(const bf16x8*)&Blo_s[wn + i * 16 + m16][kg * 8];
    }
#pragma unroll
    for (int mi = 0; mi < 4; mi++)
#pragma unroll
      for (int ni = 0; ni < 4; ni++) {
        acc[mi][ni] = __builtin_amdgcn_mfma_f32_16x16x32_bf16(ah[mi], bh[ni], acc[mi][ni], 0, 0, 0);
        acc[mi][ni] = __builtin_amdgcn_mfma_f32_16x16x32_bf16(ah[mi], bl[ni], acc[mi][ni], 0, 0, 0);
        acc[mi][ni] = __builtin_amdgcn_mfma_f32_16x16x32_bf16(al[mi], bh[ni], acc[mi][ni], 0, 0, 0);
      }
    __syncthreads();
  }

#pragma unroll
  for (int mi = 0; mi < 4; mi++) {
    float ps[4] = {0.f, 0.f, 0.f, 0.f};
#pragma unroll
    for (int ni = 0; ni < 4; ni++) {
      int col = bn0 + wn + ni * 16 + m16;
      float bb = bias ? bias[col] : 0.f;
      f32x4 v = acc[mi][ni];
#pragma unroll
      for (int j = 0; j < 4; j++) {
        float vj = v[j] + bb;
        int row = bm0 + wm + mi * 16 + kg * 4 + j;
        if (row < M) C[(size_t)row * 256 + col] = vj;
        ps[j] += vj * vj;
      }
    }
#pragma unroll
    for (int j = 0; j < 4; j++) {
      float s = ps[j];
      s += __shfl_xor(s, 1);
      s += __shfl_xor(s, 2);
      s += __shfl_xor(s, 4);
      s += __shfl_xor(s, 8);
      if (m16 == 0) {
        int row = bm0 + wm + mi * 16 + kg * 4 + j;
        if (row < M) atomicAdd(&nrm_sq[row], s);
      }
    }
  }
}

// ---- single-pass bf16 MFMA GEMM, bf16 out + fused sumsq — used for hr ----
__global__ __launch_bounds__(256) void k_gemm_bf16(const float* __restrict__ A,
                                                   const short* __restrict__ Bthi,
                                                   unsigned short* __restrict__ C16,
                                                   float* __restrict__ nrm_sq,
                                                   int M) {
  __shared__ short Ahi_s[128][GBK + 8];
  __shared__ short Bhi_s[128][GBK + 8];
  const int t    = threadIdx.x;
  const int bm0  = blockIdx.x * GBM;
  const int bn0  = blockIdx.y * GBN;
  const int wave = t >> 6, lane = t & 63;
  const int wm   = (wave >> 1) * 64, wn = (wave & 1) * 64;
  const int m16  = lane & 15, kg = lane >> 4;

  f32x4 acc[4][4] = {};

  const int srow  = t >> 1;
  const int shalf = t & 1;
  int agrow = bm0 + srow; if (agrow >= M) agrow = M - 1;
  const float* aptr   = A    + (size_t)agrow * 256 + shalf * 16;
  const short* bhiptr = Bthi + (size_t)(bn0 + srow) * 256 + shalf * 16;

  for (int k0 = 0; k0 < DIM; k0 += GBK) {
    float4 av0 = *(const float4*)(aptr + k0);
    float4 av1 = *(const float4*)(aptr + k0 + 4);
    float4 av2 = *(const float4*)(aptr + k0 + 8);
    float4 av3 = *(const float4*)(aptr + k0 + 12);
    *(bf16x8*)&Ahi_s[srow][shalf * 16 + 0] = cvt8hi(av0, av1);
    *(bf16x8*)&Ahi_s[srow][shalf * 16 + 8] = cvt8hi(av2, av3);
    *(bf16x8*)&Bhi_s[srow][shalf * 16 + 0] = *(const bf16x8*)(bhiptr + k0);
    *(bf16x8*)&Bhi_s[srow][shalf * 16 + 8] = *(const bf16x8*)(bhiptr + k0 + 8);
    __syncthreads();

    bf16x8 ah[4], bh[4];
#pragma unroll
    for (int i = 0; i < 4; i++) {
      ah[i] = *(const bf16x8*)&Ahi_s[wm + i * 16 + m16][kg * 8];
      bh[i] = *(const bf16x8*)&Bhi_s[wn + i * 16 + m16][kg * 8];
    }
#pragma unroll
    for (int mi = 0; mi < 4; mi++)
#pragma unroll
      for (int ni = 0; ni < 4; ni++)
        acc[mi][ni] = __builtin_amdgcn_mfma_f32_16x16x32_bf16(ah[mi], bh[ni], acc[mi][ni], 0, 0, 0);
    __syncthreads();
  }

#pragma unroll
  for (int mi = 0; mi < 4; mi++) {
    float ps[4] = {0.f, 0.f, 0.f, 0.f};
#pragma unroll
    for (int ni = 0; ni < 4; ni++) {
      int col = bn0 + wn + ni * 16 + m16;
      f32x4 v = acc[mi][ni];
#pragma unroll
      for (int j = 0; j < 4; j++) {
        float vj = v[j];
        int row = bm0 + wm + mi * 16 + kg * 4 + j;
        if (row < M) C16[(size_t)row * 256 + col] = f2bf_rne(vj);
        ps[j] += vj * vj;
      }
    }
#pragma unroll
    for (int j = 0; j < 4; j++) {
      float s = ps[j];
      s += __shfl_xor(s, 1);
      s += __shfl_xor(s, 2);
      s += __shfl_xor(s, 4);
      s += __shfl_xor(s, 8);
      if (m16 == 0) {
        int row = bm0 + wm + mi * 16 + kg * 4 + j;
        if (row < M) atomicAdd(&nrm_sq[row], s);
      }
    }
  }
}

// ---- pass A: bin edges into TB coarse buckets; packed entry = (src<<8)|(dst&255) ----
__global__ __launch_bounds__(1024) void k_bin(const int* __restrict__ src,
                                              const int* __restrict__ dst,
                                              int* __restrict__ cursor,
                                              int* __restrict__ binned) {
  __shared__ int hist[TB];
  __shared__ int base[TB];
  int tid = threadIdx.x;
  for (int i = tid; i < TB; i += 1024) hist[i] = 0;
  __syncthreads();
  int e0 = blockIdx.x * EPB;
  int myb[8], myrank[8], myp[8];
#pragma unroll
  for (int i = 0; i < 8; i++) {
    int e = e0 + i * 1024 + tid;
    myb[i] = -1;
    if (e < R_REL * E_EDGES) {
      int r = e / E_EDGES;
      int d = dst[e];
      int s = src[e];
      int b = r * NB + (d >> 8);
      myb[i]    = b;
      myp[i]    = (s << 8) | (d & 255);
      myrank[i] = atomicAdd(&hist[b], 1);
    }
  }
  __syncthreads();
  for (int i = tid; i < TB; i += 1024) {
    int c = hist[i];
    base[i] = c ? atomicAdd(&cursor[i], c) : 0;
  }
  __syncthreads();
#pragma unroll
  for (int i = 0; i < 8; i++) {
    if (myb[i] >= 0) {
      int pos = base[myb[i]] + myrank[i];
      if (pos < BCAP) binned[(size_t)myb[i] * BCAP + pos] = myp[i];
    }
  }
}

// ---- scan of TB bucket counts -> global bucket bases; also offsets[RN] ----
__global__ __launch_bounds__(1024) void k_bucket_scan(const int* __restrict__ cnt,
                                                      int* __restrict__ bbase,
                                                      int* __restrict__ offsets) {
  __shared__ int s[1024];
  int tid = threadIdx.x;
  int v = (tid < TB) ? cnt[tid] : 0;
  s[tid] = v;
  __syncthreads();
  for (int off = 1; off < 1024; off <<= 1) {
    int t2 = (tid >= off) ? s[tid - off] : 0;
    __syncthreads();
    s[tid] += t2;
    __syncthreads();
  }
  if (tid < TB) bbase[tid] = s[tid] - v;
  if (tid == TB - 1) offsets[RN] = s[tid];
}

// ---- pass B: per-bucket exact CSR (offsets + edge_src) ----
__global__ __launch_bounds__(256) void k_csr(const int* __restrict__ binned,
                                             const int* __restrict__ cnt_arr,
                                             const int* __restrict__ bbase,
                                             int* __restrict__ offsets,
                                             int* __restrict__ edge_src) {
  __shared__ int hist[256];
  __shared__ int excl[256];
  int b   = blockIdx.x;
  int tid = threadIdx.x;
  int cnt = cnt_arr[b]; if (cnt > BCAP) cnt = BCAP;
  int gbase = bbase[b];
  hist[tid] = 0;
  __syncthreads();
  const int* bp = binned + (size_t)b * BCAP;
  for (int i = tid; i < cnt; i += 256) atomicAdd(&hist[bp[i] & 255], 1);
  __syncthreads();
  int v = hist[tid];
  excl[tid] = v;
  __syncthreads();
  for (int off = 1; off < 256; off <<= 1) {
    int t2 = (tid >= off) ? excl[tid - off] : 0;
    __syncthreads();
    excl[tid] += t2;
    __syncthreads();
  }
  int ex = excl[tid] - v;                         // exclusive within bucket
  int r = b / NB, bloc = b % NB;
  int node = bloc * 256 + tid;
  if (node < N_NODES) offsets[r * N_NODES + node] = gbase + ex;
  hist[tid] = gbase + ex;                         // reuse as cursor
  __syncthreads();
  for (int i = tid; i < cnt; i += 256) {
    int p = bp[i];
    int pos = atomicAdd(&hist[p & 255], 1);
    edge_src[pos] = p >> 8;
  }
}

// ---- fused aggregation over all 4 relations: one wave per dst node ----
// 16-lane groups each own one edge (4 edges in flight); lane owns 16 elements.
__global__ __launch_bounds__(256) void k_aggregate_fused(
    const unsigned short* __restrict__ hr0, const unsigned short* __restrict__ hr1,
    const unsigned short* __restrict__ hr2, const unsigned short* __restrict__ hr3,
    const float* __restrict__ ht, const float* __restrict__ nsq,
    const int* __restrict__ offsets, const int* __restrict__ edge_src,
    unsigned short* __restrict__ h16, float* __restrict__ ma) {
  int n    = (int)((blockIdx.x * (size_t)blockDim.x + threadIdx.x) >> 6);
  int lane = threadIdx.x & 63;
  if (n >= N_NODES) return;
  int grp = lane >> 4, l16 = lane & 15;

  float hd[16];
  const float* htp = ht + (size_t)n * DIM + l16 * 16;
#pragma unroll
  for (int i = 0; i < 4; i++) {
    float4 v = *(const float4*)(htp + i * 4);
    hd[i * 4 + 0] = v.x; hd[i * 4 + 1] = v.y; hd[i * 4 + 2] = v.z; hd[i * 4 + 3] = v.w;
  }
  float rd = fminf(rsqrtf(nsq[n]), 1e8f);

#pragma unroll
  for (int r = 0; r < R_REL; r++) {
    const unsigned short* hr = (r == 0) ? hr0 : (r == 1) ? hr1 : (r == 2) ? hr2 : hr3;
    const float* nq = nsq + (size_t)(1 + r) * N_NODES;
    int b     = offsets[r * N_NODES + n];
    int e_end = offsets[r * N_NODES + n + 1];
    float acc[16];
#pragma unroll
    for (int i = 0; i < 16; i++) acc[i] = 0.f;
    float asum = 0.f;

    us8 ua_n = {}, ub_n = {};
    float q_n = 1.f;
    if (b < e_end) {
      int e = b + grp;
      int sn = edge_src[(e < e_end) ? e : b];
      const unsigned short* rp = hr + (size_t)sn * DIM + l16 * 16;
      ua_n = *(const us8*)rp;
      ub_n = *(const us8*)(rp + 8);
      q_n  = nq[sn];
    }
    for (int e0 = b; e0 < e_end; e0 += 4) {
      us8 ua = ua_n, ub = ub_n;
      float q = q_n;
      bool valid = (e0 + grp) < e_end;
      int e2 = e0 + 4 + grp;
      if (e2 < e_end) {
        int sn2 = edge_src[e2];
        const unsigned short* rp2 = hr + (size_t)sn2 * DIM + l16 * 16;
        ua_n = *(const us8*)rp2;
        ub_n = *(const us8*)(rp2 + 8);
        q_n  = nq[sn2];
      }
      float hs[16];
#pragma unroll
      for (int i = 0; i < 8; i++) { hs[i] = bf2f(ua[i]); hs[8 + i] = bf2f(ub[i]); }
      float num = 0.f;
#pragma unroll
      for (int i = 0; i < 16; i++) num = fmaf(hs[i], hd[i], num);
      num += __shfl_xor(num, 1);
      num += __shfl_xor(num, 2);
      num += __shfl_xor(num, 4);
      num += __shfl_xor(num, 8);
      float s = valid ? num * fminf(rsqrtf(q), 1e8f) * rd : 0.f;
#pragma unroll
      for (int i = 0; i < 16; i++) acc[i] = fmaf(s, hs[i], acc[i]);
      asum += s;
    }
    // combine the 4 edge groups
#pragma unroll
    for (int i = 0; i < 16; i++) {
      acc[i] += __shfl_xor(acc[i], 16);
      acc[i] += __shfl_xor(acc[i], 32);
    }
    asum += __shfl_xor(asum, 16);
    asum += __shfl_xor(asum, 32);
    if (grp == 0) {
      us8 o1, o2;
#pragma unroll
      for (int i = 0; i < 8; i++) { o1[i] = f2bf_rne(acc[i]); o2[i] = f2bf_rne(acc[8 + i]); }
      unsigned short* hp = h16 + ((size_t)n * R_REL + r) * DIM + l16 * 16;
      *(us8*)hp       = o1;
      *(us8*)(hp + 8) = o2;
    }
    if (lane == 0)
      ma[n * R_REL + r] = asum / fmaxf((float)(e_end - b), 1.0f);
  }
}

// ------- vulnerable nodes: mask + combine from bf16 h16 -------
__global__ __launch_bounds__(256) void k_vuln_combine(const unsigned short* __restrict__ h16,
                                                      const int* __restrict__ cand,
                                                      const float* __restrict__ ma,
                                                      float* __restrict__ out) {
  __shared__ float red[8][4];
  __shared__ float dist2s[8];
  __shared__ float sm[1024];
  int n   = blockIdx.x;
  int tid = threadIdx.x;                       // owns elements tid*4 .. tid*4+3
  ushort4 hb = *(const ushort4*)(h16 + (size_t)n * 1024 + tid * 4);
  float4 hv;
  hv.x = bf2f(hb.x); hv.y = bf2f(hb.y); hv.z = bf2f(hb.z); hv.w = bf2f(hb.w);
  float4 d2[8];
  int wid = tid >> 6, lane = tid & 63;
#pragma unroll
  for (int k = 0; k < 8; k++) {
    int c = cand[n * 8 + k];
    ushort4 cb = *(const ushort4*)(h16 + (size_t)c * 1024 + tid * 4);
    float4 df;
    df.x = hv.x - bf2f(cb.x); df.y = hv.y - bf2f(cb.y);
    df.z = hv.z - bf2f(cb.z); df.w = hv.w - bf2f(cb.w);
    d2[k].x = df.x * df.x; d2[k].y = df.y * df.y;
    d2[k].z = df.z * df.z; d2[k].w = df.w * df.w;
    float v = d2[k].x + d2[k].y + d2[k].z + d2[k].w;
    for (int off = 32; off; off >>= 1) v += __shfl_xor(v, off);
    if (lane == 0) red[k][wid] = v;
  }
  __syncthreads();
  if (tid < 32) {
    int k = tid >> 2, w2 = tid & 3;
    float v = red[k][w2];
    v += __shfl_xor(v, 1, 4);
    v += __shfl_xor(v, 2, 4);
    if (w2 == 0) dist2s[k] = v;
  }
  __syncthreads();
  float dk[8], mn = 1e30f;
#pragma unroll
  for (int k = 0; k < 8; k++) { dk[k] = sqrtf(dist2s[k]); mn = fminf(mn, dk[k]); }
  float se = 0.f, att[8];
#pragma unroll
  for (int k = 0; k < 8; k++) { att[k] = expf(mn - dk[k]); se += att[k]; }
  float inv = 1.f / se;
  float4 accv = {0.f, 0.f, 0.f, 0.f};
#pragma unroll
  for (int k = 0; k < 8; k++) {
    float a = att[k] * inv;
    accv.x += a * d2[k].x; accv.y += a * d2[k].y;
    accv.z += a * d2[k].z; accv.w += a * d2[k].w;
  }
  float m0 = ma[n * 4 + 0], m1 = ma[n * 4 + 1], m2 = ma[n * 4 + 2], m3 = ma[n * 4 + 3];
  float mx = fmaxf(fmaxf(m0, m1), fmaxf(m2, m3));
  float w0 = expf(m0 - mx), w1 = expf(m1 - mx), w2f = expf(m2 - mx), w3 = expf(m3 - mx);
  float winv = 1.f / (w0 + w1 + w2f + w3);
  float wr = (tid < 64) ? w0 : (tid < 128) ? w1 : (tid < 192) ? w2f : w3;
  float c = wr * winv;
  float4 o;
  o.x = c * hv.x * expf(-accv.x);
  o.y = c * hv.y * expf(-accv.y);
  o.z = c * hv.z * expf(-accv.z);
  o.w = c * hv.w * expf(-accv.w);
  *(float4*)&sm[tid * 4] = o;
  __syncthreads();
  if (tid < 256) {
    float v = sm[tid] + sm[256 + tid] + sm[512 + tid] + sm[768 + tid];
    out[(size_t)n * 256 + tid] = v;
  }
}

// ------- combine for non-vulnerable nodes: one wave per node, 4 nodes/block -------
__global__ __launch_bounds__(256) void k_combine_rest(const unsigned short* __restrict__ h16,
                                                      const float* __restrict__ ma,
                                                      float* __restrict__ out) {
  int n = NV_VUL + blockIdx.x * 4 + (threadIdx.x >> 6);
  if (n >= N_NODES) return;
  int lane = threadIdx.x & 63;
  float m0 = ma[n * 4 + 0], m1 = ma[n * 4 + 1], m2 = ma[n * 4 + 2], m3 = ma[n * 4 + 3];
  float mx = fmaxf(fmaxf(m0, m1), fmaxf(m2, m3));
  float w0 = expf(m0 - mx), w1 = expf(m1 - mx), w2 = expf(m2 - mx), w3 = expf(m3 - mx);
  float inv = 1.f / (w0 + w1 + w2 + w3);
  w0 *= inv; w1 *= inv; w2 *= inv; w3 *= inv;
  const unsigned short* hp = h16 + (size_t)n * 1024 + lane * 4;
  ushort4 a = *(const ushort4*)(hp);
  ushort4 b = *(const ushort4*)(hp + 256);
  ushort4 cq = *(const ushort4*)(hp + 512);
  ushort4 d = *(const ushort4*)(hp + 768);
  float4 o;
  o.x = w0 * bf2f(a.x) + w1 * bf2f(b.x) + w2 * bf2f(cq.x) + w3 * bf2f(d.x);
  o.y = w0 * bf2f(a.y) + w1 * bf2f(b.y) + w2 * bf2f(cq.y) + w3 * bf2f(d.y);
  o.z = w0 * bf2f(a.z) + w1 * bf2f(b.z) + w2 * bf2f(cq.z) + w3 * bf2f(d.z);
  o.w = w0 * bf2f(a.w) + w1 * bf2f(b.w) + w2 * bf2f(cq.w) + w3 * bf2f(d.w);
  *(float4*)(out + (size_t)n * 256 + lane * 4) = o;
}

// ---------------- diagnostic fallback ----------------
__global__ void k_fallback(float* __restrict__ out, int out_size, float wsmb) {
  int i = blockIdx.x * blockDim.x + threadIdx.x;
  if (i < out_size) out[i] = (i == 0) ? wsmb : 0.f;
}

extern "C" void kernel_launch(void* const* d_in, const int* in_sizes, int n_in,
                              void* d_out, int out_size, void* d_ws, size_t ws_size,
                              hipStream_t stream) {
  const float* x   = (const float*)d_in[0];
  const float* We  = (const float*)d_in[1];
  const float* Wn  = (const float*)d_in[2];
  const float* bnb = (const float*)d_in[3];
  const int* src   = (const int*)d_in[4];
  const int* dst   = (const int*)d_in[5];
  const int* cand  = (const int*)d_in[6];
  float* out = (float*)d_out;

  char* ws = (char*)d_ws;
  size_t off = 0;
  auto alloc = [&](size_t bytes) -> void* {
    void* p = ws + off;
    off += (bytes + 255) & ~(size_t)255;
    return p;
  };
  float*          ht          = (float*)alloc((size_t)N_NODES * DIM * 4);           // 51.2 MB
  unsigned short* h16         = (unsigned short*)alloc((size_t)N_NODES * R_REL * DIM * 2); // 102.4 MB
  float*          ma          = (float*)alloc((size_t)N_NODES * R_REL * 4);
  float*          nsq         = (float*)alloc((size_t)5 * N_NODES * 4);             // [0]=ht, [1+r]=hr
  int*            bucket_cnt  = (int*)alloc((size_t)TB * 4);
  int*            bucket_base = (int*)alloc((size_t)TB * 4);
  int*            offsets     = (int*)alloc((size_t)(RN + 1) * 4);
  int*            edge_src    = (int*)alloc((size_t)R_REL * E_EDGES * 4);           // 8 MB
  short*          Bthi        = (short*)alloc((size_t)5 * 65536 * 2);               // 0.66 MB
  short*          Btlo        = (short*)alloc((size_t)65536 * 2);                   // 0.13 MB
  unsigned short* hr2         = (unsigned short*)alloc((size_t)N_NODES * DIM * 2);  // 25.6 MB
  unsigned short* hr3         = (unsigned short*)alloc((size_t)N_NODES * DIM * 2);  // 25.6 MB
  size_t required = off;
  (void)in_sizes; (void)n_in;

  if (ws_size < required) {
    k_fallback<<<(out_size + 255) / 256, 256, 0, stream>>>(out, out_size,
                                                           (float)(ws_size >> 20));
    return;
  }

  // d_out scratch: hr0 at [0, 25.6MB), hr1 at [25.6, 51.2MB). Dead before the
  // final combine kernels overwrite out (stream-ordered).
  unsigned short* hr0 = (unsigned short*)out;
  unsigned short* hr1 = hr0 + (size_t)N_NODES * DIM;
  int* binned = (int*)h16;       // 16.06 MB bin staging aliases h16 (dead before aggregate)

  hipMemsetAsync(bucket_cnt, 0, (size_t)TB * 4, stream);
  hipMemsetAsync(nsq, 0, (size_t)5 * N_NODES * 4, stream);

  k_convert_w<<<dim3(4, 4, 5), 256, 0, stream>>>(Wn, We, Bthi, Btlo);

  dim3 gemm_grid((N_NODES + GBM - 1) / GBM, DIM / GBN);

  // ht = x @ Wn + bn (3-pass split-bf16 MFMA, fp32 out), fused sumsq
  k_gemm_mfma<<<gemm_grid, 256, 0, stream>>>(x, Bthi, Btlo, bnb, ht, nsq, N_NODES);

  // binned CSR build: bin -> bucket scan -> per-bucket CSR
  k_bin<<<(R_REL * E_EDGES + EPB - 1) / EPB, 1024, 0, stream>>>(src, dst, bucket_cnt, binned);
  k_bucket_scan<<<1, 1024, 0, stream>>>(bucket_cnt, bucket_base, offsets);
  k_csr<<<TB, 256, 0, stream>>>(binned, bucket_cnt, bucket_base, offsets, edge_src);

  // hr16[r] = bf16(x @ We[r]) (1-pass MFMA) + fused sumsq
  unsigned short* hrs[4] = {hr0, hr1, hr2, hr3};
  for (int r = 0; r < R_REL; r++)
    k_gemm_bf16<<<gemm_grid, 256, 0, stream>>>(x, Bthi + (size_t)(1 + r) * 65536,
                                               hrs[r], nsq + (size_t)(1 + r) * N_NODES, N_NODES);

  // fused aggregation over all relations (reads ht once; writes bf16 h)
  k_aggregate_fused<<<(N_NODES * 64 + 255) / 256, 256, 0, stream>>>(
      hr0, hr1, hr2, hr3, ht, nsq, offsets, edge_src, h16, ma);

  // vulnerable nodes: mask + combine (reads h16, writes out rows [0, NV))
  k_vuln_combine<<<NV_VUL, 256, 0, stream>>>(h16, cand, ma, out);

  // non-vulnerable nodes: combine (writes out rows [NV, N))
  k_combine_rest<<<(N_NODES - NV_VUL + 3) / 4, 256, 0, stream>>>(h16, ma, out);
}

// Round 8
// 481.326 us; speedup vs baseline: 2.7467x; 1.0083x over previous
//
#include <hip/hip_runtime.h>

#define N_NODES 50000
#define DIM     256
#define R_REL   4
#define E_EDGES 500000
#define NV_VUL  10000
#define K_CAND  8
#define EPS_C   1e-8f
#define RN      (R_REL * N_NODES)            // 200000
#define NB      196                          // buckets per relation (256 nodes each)
#define TB      (R_REL * NB)                 // 784 total buckets
#define BCAP    5120                         // capacity per bucket (mean 2551)
#define EPB     8192                         // edges per k_bin block

typedef short bf16x8 __attribute__((ext_vector_type(8)));
typedef float f32x4  __attribute__((ext_vector_type(4)));
typedef float f32x2  __attribute__((ext_vector_type(2)));
typedef unsigned short us8 __attribute__((ext_vector_type(8)));

__device__ __forceinline__ unsigned short f2bf_rne(float f) {
  unsigned u = __builtin_bit_cast(unsigned, f);
  unsigned r = (u + 0x7FFFu + ((u >> 16) & 1u)) >> 16;
  return (unsigned short)r;
}
__device__ __forceinline__ float bf2f(unsigned short h) {
  unsigned u = ((unsigned)h) << 16;
  return __builtin_bit_cast(float, u);
}
// one dword holding 2 bf16 -> float2 {elem_lo, elem_hi}
__device__ __forceinline__ f32x2 expand_bf2(unsigned dw) {
  f32x2 v;
  v.x = __builtin_bit_cast(float, dw << 16);
  v.y = __builtin_bit_cast(float, dw & 0xFFFF0000u);
  return v;
}
__device__ __forceinline__ bf16x8 cvt8hi(float4 a, float4 b) {
  float f[8] = {a.x, a.y, a.z, a.w, b.x, b.y, b.z, b.w};
  bf16x8 hh;
#pragma unroll
  for (int i = 0; i < 8; i++) hh[i] = (short)f2bf_rne(f[i]);
  return hh;
}

// ---- weight prep: Bt_hi[w][n][k] = bf16(W_w[k][n]) ----
__global__ __launch_bounds__(256) void k_convert_w(const float* __restrict__ Wn,
                                                   const float* __restrict__ We,
                                                   short* __restrict__ Bthi) {
  __shared__ float tile[64][65];
  int w  = blockIdx.z;                    // 0 = Wn, 1..4 = We[w-1]
  int k0 = blockIdx.x * 64, n0 = blockIdx.y * 64;
  const float* W = (w == 0) ? Wn : We + (size_t)(w - 1) * 65536;
  int tx = threadIdx.x & 63, ty = threadIdx.x >> 6;
  for (int i = ty; i < 64; i += 4)
    tile[i][tx] = W[(size_t)(k0 + i) * 256 + n0 + tx];
  __syncthreads();
  for (int i = ty; i < 64; i += 4) {
    float f = tile[tx][i];                // = W[k0+tx][n0+i]
    size_t o = (size_t)w * 65536 + (size_t)(n0 + i) * 256 + k0 + tx;
    Bthi[o] = (short)f2bf_rne(f);
  }
}

#define GBM 128
#define GBN 128
#define GBK 32
// ---- single-pass bf16 MFMA GEMM, bf16 out (+optional bias) + fused sumsq ----
__global__ __launch_bounds__(256) void k_gemm_bf16(const float* __restrict__ A,
                                                   const short* __restrict__ Bthi,
                                                   const float* __restrict__ bias,
                                                   unsigned short* __restrict__ C16,
                                                   float* __restrict__ nrm_sq,
                                                   int M) {
  __shared__ short Ahi_s[128][GBK + 8];
  __shared__ short Bhi_s[128][GBK + 8];
  const int t    = threadIdx.x;
  const int bm0  = blockIdx.x * GBM;
  const int bn0  = blockIdx.y * GBN;
  const int wave = t >> 6, lane = t & 63;
  const int wm   = (wave >> 1) * 64, wn = (wave & 1) * 64;
  const int m16  = lane & 15, kg = lane >> 4;

  f32x4 acc[4][4] = {};

  const int srow  = t >> 1;
  const int shalf = t & 1;
  int agrow = bm0 + srow; if (agrow >= M) agrow = M - 1;
  const float* aptr   = A    + (size_t)agrow * 256 + shalf * 16;
  const short* bhiptr = Bthi + (size_t)(bn0 + srow) * 256 + shalf * 16;

  for (int k0 = 0; k0 < DIM; k0 += GBK) {
    float4 av0 = *(const float4*)(aptr + k0);
    float4 av1 = *(const float4*)(aptr + k0 + 4);
    float4 av2 = *(const float4*)(aptr + k0 + 8);
    float4 av3 = *(const float4*)(aptr + k0 + 12);
    *(bf16x8*)&Ahi_s[srow][shalf * 16 + 0] = cvt8hi(av0, av1);
    *(bf16x8*)&Ahi_s[srow][shalf * 16 + 8] = cvt8hi(av2, av3);
    *(bf16x8*)&Bhi_s[srow][shalf * 16 + 0] = *(const bf16x8*)(bhiptr + k0);
    *(bf16x8*)&Bhi_s[srow][shalf * 16 + 8] = *(const bf16x8*)(bhiptr + k0 + 8);
    __syncthreads();

    bf16x8 ah[4], bh[4];
#pragma unroll
    for (int i = 0; i < 4; i++) {
      ah[i] = *(const bf16x8*)&Ahi_s[wm + i * 16 + m16][kg * 8];
      bh[i] = *(const bf16x8*)&Bhi_s[wn + i * 16 + m16][kg * 8];
    }
#pragma unroll
    for (int mi = 0; mi < 4; mi++)
#pragma unroll
      for (int ni = 0; ni < 4; ni++)
        acc[mi][ni] = __builtin_amdgcn_mfma_f32_16x16x32_bf16(ah[mi], bh[ni], acc[mi][ni], 0, 0, 0);
    __syncthreads();
  }

#pragma unroll
  for (int mi = 0; mi < 4; mi++) {
    float ps[4] = {0.f, 0.f, 0.f, 0.f};
#pragma unroll
    for (int ni = 0; ni < 4; ni++) {
      int col = bn0 + wn + ni * 16 + m16;
      float bb = bias ? bias[col] : 0.f;
      f32x4 v = acc[mi][ni];
#pragma unroll
      for (int j = 0; j < 4; j++) {
        float vj = v[j] + bb;
        int row = bm0 + wm + mi * 16 + kg * 4 + j;
        if (row < M) C16[(size_t)row * 256 + col] = f2bf_rne(vj);
        ps[j] += vj * vj;
      }
    }
#pragma unroll
    for (int j = 0; j < 4; j++) {
      float s = ps[j];
      s += __shfl_xor(s, 1);
      s += __shfl_xor(s, 2);
      s += __shfl_xor(s, 4);
      s += __shfl_xor(s, 8);
      if (m16 == 0) {
        int row = bm0 + wm + mi * 16 + kg * 4 + j;
        if (row < M) atomicAdd(&nrm_sq[row], s);
      }
    }
  }
}

// ---- pass A: bin edges into TB coarse buckets; packed entry = (src<<8)|(dst&255) ----
__global__ __launch_bounds__(1024) void k_bin(const int* __restrict__ src,
                                              const int* __restrict__ dst,
                                              int* __restrict__ cursor,
                                              int* __restrict__ binned) {
  __shared__ int hist[TB];
  __shared__ int base[TB];
  int tid = threadIdx.x;
  for (int i = tid; i < TB; i += 1024) hist[i] = 0;
  __syncthreads();
  int e0 = blockIdx.x * EPB;
  int myb[8], myrank[8], myp[8];
#pragma unroll
  for (int i = 0; i < 8; i++) {
    int e = e0 + i * 1024 + tid;
    myb[i] = -1;
    if (e < R_REL * E_EDGES) {
      int r = e / E_EDGES;
      int d = dst[e];
      int s = src[e];
      int b = r * NB + (d >> 8);
      myb[i]    = b;
      myp[i]    = (s << 8) | (d & 255);
      myrank[i] = atomicAdd(&hist[b], 1);
    }
  }
  __syncthreads();
  for (int i = tid; i < TB; i += 1024) {
    int c = hist[i];
    base[i] = c ? atomicAdd(&cursor[i], c) : 0;
  }
  __syncthreads();
#pragma unroll
  for (int i = 0; i < 8; i++) {
    if (myb[i] >= 0) {
      int pos = base[myb[i]] + myrank[i];
      if (pos < BCAP) binned[(size_t)myb[i] * BCAP + pos] = myp[i];
    }
  }
}

// ---- scan of TB bucket counts -> global bucket bases; also offsets[RN] ----
__global__ __launch_bounds__(1024) void k_bucket_scan(const int* __restrict__ cnt,
                                                      int* __restrict__ bbase,
                                                      int* __restrict__ offsets) {
  __shared__ int s[1024];
  int tid = threadIdx.x;
  int v = (tid < TB) ? cnt[tid] : 0;
  s[tid] = v;
  __syncthreads();
  for (int off = 1; off < 1024; off <<= 1) {
    int t2 = (tid >= off) ? s[tid - off] : 0;
    __syncthreads();
    s[tid] += t2;
    __syncthreads();
  }
  if (tid < TB) bbase[tid] = s[tid] - v;
  if (tid == TB - 1) offsets[RN] = s[tid];
}

// ---- pass B: per-bucket exact CSR (offsets + edge_src) ----
__global__ __launch_bounds__(256) void k_csr(const int* __restrict__ binned,
                                             const int* __restrict__ cnt_arr,
                                             const int* __restrict__ bbase,
                                             int* __restrict__ offsets,
                                             int* __restrict__ edge_src) {
  __shared__ int hist[256];
  __shared__ int excl[256];
  int b   = blockIdx.x;
  int tid = threadIdx.x;
  int cnt = cnt_arr[b]; if (cnt > BCAP) cnt = BCAP;
  int gbase = bbase[b];
  hist[tid] = 0;
  __syncthreads();
  const int* bp = binned + (size_t)b * BCAP;
  for (int i = tid; i < cnt; i += 256) atomicAdd(&hist[bp[i] & 255], 1);
  __syncthreads();
  int v = hist[tid];
  excl[tid] = v;
  __syncthreads();
  for (int off = 1; off < 256; off <<= 1) {
    int t2 = (tid >= off) ? excl[tid - off] : 0;
    __syncthreads();
    excl[tid] += t2;
    __syncthreads();
  }
  int ex = excl[tid] - v;                         // exclusive within bucket
  int r = b / NB, bloc = b % NB;
  int node = bloc * 256 + tid;
  if (node < N_NODES) offsets[r * N_NODES + node] = gbase + ex;
  hist[tid] = gbase + ex;                         // reuse as cursor
  __syncthreads();
  for (int i = tid; i < cnt; i += 256) {
    int p = bp[i];
    int pos = atomicAdd(&hist[p & 255], 1);
    edge_src[pos] = p >> 8;
  }
}

// ---- fused aggregation over all 4 relations: one wave per dst node ----
// 16-lane groups each own one edge (4 edges in flight); lane owns 16 elements
// handled as 8 packed float2 (v_pk_fma_f32 path).
__global__ __launch_bounds__(256) void k_aggregate_fused(
    const unsigned short* __restrict__ hr0, const unsigned short* __restrict__ hr1,
    const unsigned short* __restrict__ hr2, const unsigned short* __restrict__ hr3,
    const unsigned short* __restrict__ ht16, const float* __restrict__ nsq,
    const int* __restrict__ offsets, const int* __restrict__ edge_src,
    unsigned short* __restrict__ h16, float* __restrict__ ma) {
  int n    = (int)((blockIdx.x * (size_t)blockDim.x + threadIdx.x) >> 6);
  int lane = threadIdx.x & 63;
  if (n >= N_NODES) return;
  int grp = lane >> 4, l16 = lane & 15;

  const uint4* htp = (const uint4*)(ht16 + (size_t)n * DIM + l16 * 16);
  uint4 hta = htp[0], htb = htp[1];
  f32x2 hd2[8];
  hd2[0] = expand_bf2(hta.x); hd2[1] = expand_bf2(hta.y);
  hd2[2] = expand_bf2(hta.z); hd2[3] = expand_bf2(hta.w);
  hd2[4] = expand_bf2(htb.x); hd2[5] = expand_bf2(htb.y);
  hd2[6] = expand_bf2(htb.z); hd2[7] = expand_bf2(htb.w);
  float rd = fminf(rsqrtf(nsq[n]), 1e8f);

#pragma unroll
  for (int r = 0; r < R_REL; r++) {
    const unsigned short* hr = (r == 0) ? hr0 : (r == 1) ? hr1 : (r == 2) ? hr2 : hr3;
    const float* nq = nsq + (size_t)(1 + r) * N_NODES;
    int b     = offsets[r * N_NODES + n];
    int e_end = offsets[r * N_NODES + n + 1];
    f32x2 acc2[8] = {};
    float asum = 0.f;

    uint4 ua_n = {}, ub_n = {};
    float q_n = 1.f;
    if (b < e_end) {
      int e = b + grp;
      int sn = edge_src[(e < e_end) ? e : b];
      const uint4* rp = (const uint4*)(hr + (size_t)sn * DIM + l16 * 16);
      ua_n = rp[0]; ub_n = rp[1];
      q_n  = nq[sn];
    }
    for (int e0 = b; e0 < e_end; e0 += 4) {
      uint4 ua = ua_n, ub = ub_n;
      float q = q_n;
      bool valid = (e0 + grp) < e_end;
      int e2 = e0 + 4 + grp;
      if (e2 < e_end) {
        int sn2 = edge_src[e2];
        const uint4* rp2 = (const uint4*)(hr + (size_t)sn2 * DIM + l16 * 16);
        ua_n = rp2[0]; ub_n = rp2[1];
        q_n  = nq[sn2];
      }
      f32x2 hs2[8];
      hs2[0] = expand_bf2(ua.x); hs2[1] = expand_bf2(ua.y);
      hs2[2] = expand_bf2(ua.z); hs2[3] = expand_bf2(ua.w);
      hs2[4] = expand_bf2(ub.x); hs2[5] = expand_bf2(ub.y);
      hs2[6] = expand_bf2(ub.z); hs2[7] = expand_bf2(ub.w);
      f32x2 d2 = hs2[0] * hd2[0];
#pragma unroll
      for (int i = 1; i < 8; i++) d2 += hs2[i] * hd2[i];
      float num = d2.x + d2.y;
      num += __shfl_xor(num, 1);
      num += __shfl_xor(num, 2);
      num += __shfl_xor(num, 4);
      num += __shfl_xor(num, 8);
      float s = valid ? num * fminf(rsqrtf(q), 1e8f) * rd : 0.f;
      f32x2 s2 = {s, s};
#pragma unroll
      for (int i = 0; i < 8; i++) acc2[i] += hs2[i] * s2;
      asum += s;
    }
    // combine the 4 edge groups
#pragma unroll
    for (int i = 0; i < 8; i++) {
      float ax = acc2[i].x, ay = acc2[i].y;
      ax += __shfl_xor(ax, 16); ax += __shfl_xor(ax, 32);
      ay += __shfl_xor(ay, 16); ay += __shfl_xor(ay, 32);
      acc2[i].x = ax; acc2[i].y = ay;
    }
    asum += __shfl_xor(asum, 16);
    asum += __shfl_xor(asum, 32);
    if (grp == 0) {
      us8 o1, o2;
#pragma unroll
      for (int i = 0; i < 4; i++) {
        o1[2 * i]     = f2bf_rne(acc2[i].x);
        o1[2 * i + 1] = f2bf_rne(acc2[i].y);
        o2[2 * i]     = f2bf_rne(acc2[4 + i].x);
        o2[2 * i + 1] = f2bf_rne(acc2[4 + i].y);
      }
      unsigned short* hp = h16 + ((size_t)n * R_REL + r) * DIM + l16 * 16;
      *(us8*)hp       = o1;
      *(us8*)(hp + 8) = o2;
    }
    if (lane == 0)
      ma[n * R_REL + r] = asum / fmaxf((float)(e_end - b), 1.0f);
  }
}

// ------- vulnerable nodes: mask + combine from bf16 h16 -------
__global__ __launch_bounds__(256) void k_vuln_combine(const unsigned short* __restrict__ h16,
                                                      const int* __restrict__ cand,
                                                      const float* __restrict__ ma,
                                                      float* __restrict__ out) {
  __shared__ float red[8][4];
  __shared__ float dist2s[8];
  __shared__ float sm[1024];
  int n   = blockIdx.x;
  int tid = threadIdx.x;                       // owns elements tid*4 .. tid*4+3
  ushort4 hb = *(const ushort4*)(h16 + (size_t)n * 1024 + tid * 4);
  float4 hv;
  hv.x = bf2f(hb.x); hv.y = bf2f(hb.y); hv.z = bf2f(hb.z); hv.w = bf2f(hb.w);
  float4 d2[8];
  int wid = tid >> 6, lane = tid & 63;
#pragma unroll
  for (int k = 0; k < 8; k++) {
    int c = cand[n * 8 + k];
    ushort4 cb = *(const ushort4*)(h16 + (size_t)c * 1024 + tid * 4);
    float4 df;
    df.x = hv.x - bf2f(cb.x); df.y = hv.y - bf2f(cb.y);
    df.z = hv.z - bf2f(cb.z); df.w = hv.w - bf2f(cb.w);
    d2[k].x = df.x * df.x; d2[k].y = df.y * df.y;
    d2[k].z = df.z * df.z; d2[k].w = df.w * df.w;
    float v = d2[k].x + d2[k].y + d2[k].z + d2[k].w;
    for (int off = 32; off; off >>= 1) v += __shfl_xor(v, off);
    if (lane == 0) red[k][wid] = v;
  }
  __syncthreads();
  if (tid < 32) {
    int k = tid >> 2, w2 = tid & 3;
    float v = red[k][w2];
    v += __shfl_xor(v, 1, 4);
    v += __shfl_xor(v, 2, 4);
    if (w2 == 0) dist2s[k] = v;
  }
  __syncthreads();
  float dk[8], mn = 1e30f;
#pragma unroll
  for (int k = 0; k < 8; k++) { dk[k] = sqrtf(dist2s[k]); mn = fminf(mn, dk[k]); }
  float se = 0.f, att[8];
#pragma unroll
  for (int k = 0; k < 8; k++) { att[k] = expf(mn - dk[k]); se += att[k]; }
  float inv = 1.f / se;
  float4 accv = {0.f, 0.f, 0.f, 0.f};
#pragma unroll
  for (int k = 0; k < 8; k++) {
    float a = att[k] * inv;
    accv.x += a * d2[k].x; accv.y += a * d2[k].y;
    accv.z += a * d2[k].z; accv.w += a * d2[k].w;
  }
  float m0 = ma[n * 4 + 0], m1 = ma[n * 4 + 1], m2 = ma[n * 4 + 2], m3 = ma[n * 4 + 3];
  float mx = fmaxf(fmaxf(m0, m1), fmaxf(m2, m3));
  float w0 = expf(m0 - mx), w1 = expf(m1 - mx), w2f = expf(m2 - mx), w3 = expf(m3 - mx);
  float winv = 1.f / (w0 + w1 + w2f + w3);
  float wr = (tid < 64) ? w0 : (tid < 128) ? w1 : (tid < 192) ? w2f : w3;
  float c = wr * winv;
  float4 o;
  o.x = c * hv.x * expf(-accv.x);
  o.y = c * hv.y * expf(-accv.y);
  o.z = c * hv.z * expf(-accv.z);
  o.w = c * hv.w * expf(-accv.w);
  *(float4*)&sm[tid * 4] = o;
  __syncthreads();
  if (tid < 256) {
    float v = sm[tid] + sm[256 + tid] + sm[512 + tid] + sm[768 + tid];
    out[(size_t)n * 256 + tid] = v;
  }
}

// ------- combine for non-vulnerable nodes: one wave per node, 4 nodes/block -------
__global__ __launch_bounds__(256) void k_combine_rest(const unsigned short* __restrict__ h16,
                                                      const float* __restrict__ ma,
                                                      float* __restrict__ out) {
  int n = NV_VUL + blockIdx.x * 4 + (threadIdx.x >> 6);
  if (n >= N_NODES) return;
  int lane = threadIdx.x & 63;
  float m0 = ma[n * 4 + 0], m1 = ma[n * 4 + 1], m2 = ma[n * 4 + 2], m3 = ma[n * 4 + 3];
  float mx = fmaxf(fmaxf(m0, m1), fmaxf(m2, m3));
  float w0 = expf(m0 - mx), w1 = expf(m1 - mx), w2 = expf(m2 - mx), w3 = expf(m3 - mx);
  float inv = 1.f / (w0 + w1 + w2 + w3);
  w0 *= inv; w1 *= inv; w2 *= inv; w3 *= inv;
  const unsigned short* hp = h16 + (size_t)n * 1024 + lane * 4;
  ushort4 a = *(const ushort4*)(hp);
  ushort4 b = *(const ushort4*)(hp + 256);
  ushort4 cq = *(const ushort4*)(hp + 512);
  ushort4 d = *(const ushort4*)(hp + 768);
  float4 o;
  o.x = w0 * bf2f(a.x) + w1 * bf2f(b.x) + w2 * bf2f(cq.x) + w3 * bf2f(d.x);
  o.y = w0 * bf2f(a.y) + w1 * bf2f(b.y) + w2 * bf2f(cq.y) + w3 * bf2f(d.y);
  o.z = w0 * bf2f(a.z) + w1 * bf2f(b.z) + w2 * bf2f(cq.z) + w3 * bf2f(d.z);
  o.w = w0 * bf2f(a.w) + w1 * bf2f(b.w) + w2 * bf2f(cq.w) + w3 * bf2f(d.w);
  *(float4*)(out + (size_t)n * 256 + lane * 4) = o;
}

// ---------------- diagnostic fallback ----------------
__global__ void k_fallback(float* __restrict__ out, int out_size, float wsmb) {
  int i = blockIdx.x * blockDim.x + threadIdx.x;
  if (i < out_size) out[i] = (i == 0) ? wsmb : 0.f;
}

extern "C" void kernel_launch(void* const* d_in, const int* in_sizes, int n_in,
                              void* d_out, int out_size, void* d_ws, size_t ws_size,
                              hipStream_t stream) {
  const float* x   = (const float*)d_in[0];
  const float* We  = (const float*)d_in[1];
  const float* Wn  = (const float*)d_in[2];
  const float* bnb = (const float*)d_in[3];
  const int* src   = (const int*)d_in[4];
  const int* dst   = (const int*)d_in[5];
  const int* cand  = (const int*)d_in[6];
  float* out = (float*)d_out;

  char* ws = (char*)d_ws;
  size_t off = 0;
  auto alloc = [&](size_t bytes) -> void* {
    void* p = ws + off;
    off += (bytes + 255) & ~(size_t)255;
    return p;
  };
  unsigned short* ht16        = (unsigned short*)alloc((size_t)N_NODES * DIM * 2);          // 25.6 MB
  unsigned short* h16         = (unsigned short*)alloc((size_t)N_NODES * R_REL * DIM * 2);  // 102.4 MB
  float*          ma          = (float*)alloc((size_t)N_NODES * R_REL * 4);
  float*          nsq         = (float*)alloc((size_t)5 * N_NODES * 4);                     // [0]=ht, [1+r]=hr
  int*            bucket_cnt  = (int*)alloc((size_t)TB * 4);
  int*            bucket_base = (int*)alloc((size_t)TB * 4);
  int*            offsets     = (int*)alloc((size_t)(RN + 1) * 4);
  int*            edge_src    = (int*)alloc((size_t)R_REL * E_EDGES * 4);                   // 8 MB
  short*          Bthi        = (short*)alloc((size_t)5 * 65536 * 2);                       // 0.66 MB
  unsigned short* hr2         = (unsigned short*)alloc((size_t)N_NODES * DIM * 2);          // 25.6 MB
  unsigned short* hr3         = (unsigned short*)alloc((size_t)N_NODES * DIM * 2);          // 25.6 MB
  size_t required = off;
  (void)in_sizes; (void)n_in;

  if (ws_size < required) {
    k_fallback<<<(out_size + 255) / 256, 256, 0, stream>>>(out, out_size,
                                                           (float)(ws_size >> 20));
    return;
  }

  // d_out scratch: hr0 at [0, 25.6MB), hr1 at [25.6, 51.2MB). Dead before the
  // final combine kernels overwrite out (stream-ordered).
  unsigned short* hr0 = (unsigned short*)out;
  unsigned short* hr1 = hr0 + (size_t)N_NODES * DIM;
  int* binned = (int*)h16;       // 16.06 MB bin staging aliases h16 (dead before aggregate)

  hipMemsetAsync(bucket_cnt, 0, (size_t)TB * 4, stream);
  hipMemsetAsync(nsq, 0, (size_t)5 * N_NODES * 4, stream);

  k_convert_w<<<dim3(4, 4, 5), 256, 0, stream>>>(Wn, We, Bthi);

  dim3 gemm_grid((N_NODES + GBM - 1) / GBM, DIM / GBN);

  // ht16 = bf16(x @ Wn + bn) (1-pass MFMA), fused sumsq
  k_gemm_bf16<<<gemm_grid, 256, 0, stream>>>(x, Bthi, bnb, ht16, nsq, N_NODES);

  // binned CSR build: bin -> bucket scan -> per-bucket CSR
  k_bin<<<(R_REL * E_EDGES + EPB - 1) / EPB, 1024, 0, stream>>>(src, dst, bucket_cnt, binned);
  k_bucket_scan<<<1, 1024, 0, stream>>>(bucket_cnt, bucket_base, offsets);
  k_csr<<<TB, 256, 0, stream>>>(binned, bucket_cnt, bucket_base, offsets, edge_src);

  // hr16[r] = bf16(x @ We[r]) (1-pass MFMA) + fused sumsq
  unsigned short* hrs[4] = {hr0, hr1, hr2, hr3};
  for (int r = 0; r < R_REL; r++)
    k_gemm_bf16<<<gemm_grid, 256, 0, stream>>>(x, Bthi + (size_t)(1 + r) * 65536, nullptr,
                                               hrs[r], nsq + (size_t)(1 + r) * N_NODES, N_NODES);

  // fused aggregation over all relations (reads ht16 once; writes bf16 h)
  k_aggregate_fused<<<(N_NODES * 64 + 255) / 256, 256, 0, stream>>>(
      hr0, hr1, hr2, hr3, ht16, nsq, offsets, edge_src, h16, ma);

  // vulnerable nodes: mask + combine (reads h16, writes out rows [0, NV))
  k_vuln_combine<<<NV_VUL, 256, 0, stream>>>(h16, cand, ma, out);

  // non-vulnerable nodes: combine (writes out rows [NV, N))
  k_combine_rest<<<(N_NODES - NV_VUL + 3) / 4, 256, 0, stream>>>(h16, ma, out);
}

// Round 9
// 458.919 us; speedup vs baseline: 2.8808x; 1.0488x over previous
//
#include <hip/hip_runtime.h>

#define N_NODES 50000
#define DIM     256
#define R_REL   4
#define E_EDGES 500000
#define NV_VUL  10000
#define K_CAND  8
#define EPS_C   1e-8f
#define RN      (R_REL * N_NODES)            // 200000
#define NB      196                          // buckets per relation (256 nodes each)
#define TB      (R_REL * NB)                 // 784 total buckets
#define BCAP    5120                         // capacity per bucket (mean 2551)
#define EPB     8192                         // edges per k_bin block

typedef short bf16x8 __attribute__((ext_vector_type(8)));
typedef float f32x4  __attribute__((ext_vector_type(4)));
typedef float f32x2  __attribute__((ext_vector_type(2)));
typedef unsigned short us8 __attribute__((ext_vector_type(8)));

__device__ __forceinline__ unsigned short f2bf_rne(float f) {
  unsigned u = __builtin_bit_cast(unsigned, f);
  unsigned r = (u + 0x7FFFu + ((u >> 16) & 1u)) >> 16;
  return (unsigned short)r;
}
__device__ __forceinline__ float bf2f(unsigned short h) {
  unsigned u = ((unsigned)h) << 16;
  return __builtin_bit_cast(float, u);
}
// one dword holding 2 bf16 -> float2 {elem_lo, elem_hi}
__device__ __forceinline__ f32x2 expand_bf2(unsigned dw) {
  f32x2 v;
  v.x = __builtin_bit_cast(float, dw << 16);
  v.y = __builtin_bit_cast(float, dw & 0xFFFF0000u);
  return v;
}
__device__ __forceinline__ bf16x8 cvt8hi(float4 a, float4 b) {
  float f[8] = {a.x, a.y, a.z, a.w, b.x, b.y, b.z, b.w};
  bf16x8 hh;
#pragma unroll
  for (int i = 0; i < 8; i++) hh[i] = (short)f2bf_rne(f[i]);
  return hh;
}

// ---- weight prep: Bt_hi[w][n][k] = bf16(W_w[k][n]) ----
__global__ __launch_bounds__(256) void k_convert_w(const float* __restrict__ Wn,
                                                   const float* __restrict__ We,
                                                   short* __restrict__ Bthi) {
  __shared__ float tile[64][65];
  int w  = blockIdx.z;                    // 0 = Wn, 1..4 = We[w-1]
  int k0 = blockIdx.x * 64, n0 = blockIdx.y * 64;
  const float* W = (w == 0) ? Wn : We + (size_t)(w - 1) * 65536;
  int tx = threadIdx.x & 63, ty = threadIdx.x >> 6;
  for (int i = ty; i < 64; i += 4)
    tile[i][tx] = W[(size_t)(k0 + i) * 256 + n0 + tx];
  __syncthreads();
  for (int i = ty; i < 64; i += 4) {
    float f = tile[tx][i];                // = W[k0+tx][n0+i]
    size_t o = (size_t)w * 65536 + (size_t)(n0 + i) * 256 + k0 + tx;
    Bthi[o] = (short)f2bf_rne(f);
  }
}

#define GBM 128
#define GBN 128
#define GBK 32
// ---- single-pass bf16 MFMA GEMM, bf16 out (+optional bias) + fused sumsq ----
__global__ __launch_bounds__(256) void k_gemm_bf16(const float* __restrict__ A,
                                                   const short* __restrict__ Bthi,
                                                   const float* __restrict__ bias,
                                                   unsigned short* __restrict__ C16,
                                                   float* __restrict__ nrm_sq,
                                                   int M) {
  __shared__ short Ahi_s[128][GBK + 8];
  __shared__ short Bhi_s[128][GBK + 8];
  const int t    = threadIdx.x;
  const int bm0  = blockIdx.x * GBM;
  const int bn0  = blockIdx.y * GBN;
  const int wave = t >> 6, lane = t & 63;
  const int wm   = (wave >> 1) * 64, wn = (wave & 1) * 64;
  const int m16  = lane & 15, kg = lane >> 4;

  f32x4 acc[4][4] = {};

  const int srow  = t >> 1;
  const int shalf = t & 1;
  int agrow = bm0 + srow; if (agrow >= M) agrow = M - 1;
  const float* aptr   = A    + (size_t)agrow * 256 + shalf * 16;
  const short* bhiptr = Bthi + (size_t)(bn0 + srow) * 256 + shalf * 16;

  for (int k0 = 0; k0 < DIM; k0 += GBK) {
    float4 av0 = *(const float4*)(aptr + k0);
    float4 av1 = *(const float4*)(aptr + k0 + 4);
    float4 av2 = *(const float4*)(aptr + k0 + 8);
    float4 av3 = *(const float4*)(aptr + k0 + 12);
    *(bf16x8*)&Ahi_s[srow][shalf * 16 + 0] = cvt8hi(av0, av1);
    *(bf16x8*)&Ahi_s[srow][shalf * 16 + 8] = cvt8hi(av2, av3);
    *(bf16x8*)&Bhi_s[srow][shalf * 16 + 0] = *(const bf16x8*)(bhiptr + k0);
    *(bf16x8*)&Bhi_s[srow][shalf * 16 + 8] = *(const bf16x8*)(bhiptr + k0 + 8);
    __syncthreads();

    bf16x8 ah[4], bh[4];
#pragma unroll
    for (int i = 0; i < 4; i++) {
      ah[i] = *(const bf16x8*)&Ahi_s[wm + i * 16 + m16][kg * 8];
      bh[i] = *(const bf16x8*)&Bhi_s[wn + i * 16 + m16][kg * 8];
    }
#pragma unroll
    for (int mi = 0; mi < 4; mi++)
#pragma unroll
      for (int ni = 0; ni < 4; ni++)
        acc[mi][ni] = __builtin_amdgcn_mfma_f32_16x16x32_bf16(ah[mi], bh[ni], acc[mi][ni], 0, 0, 0);
    __syncthreads();
  }

#pragma unroll
  for (int mi = 0; mi < 4; mi++) {
    float ps[4] = {0.f, 0.f, 0.f, 0.f};
#pragma unroll
    for (int ni = 0; ni < 4; ni++) {
      int col = bn0 + wn + ni * 16 + m16;
      float bb = bias ? bias[col] : 0.f;
      f32x4 v = acc[mi][ni];
#pragma unroll
      for (int j = 0; j < 4; j++) {
        float vj = v[j] + bb;
        int row = bm0 + wm + mi * 16 + kg * 4 + j;
        if (row < M) C16[(size_t)row * 256 + col] = f2bf_rne(vj);
        ps[j] += vj * vj;
      }
    }
#pragma unroll
    for (int j = 0; j < 4; j++) {
      float s = ps[j];
      s += __shfl_xor(s, 1);
      s += __shfl_xor(s, 2);
      s += __shfl_xor(s, 4);
      s += __shfl_xor(s, 8);
      if (m16 == 0) {
        int row = bm0 + wm + mi * 16 + kg * 4 + j;
        if (row < M) atomicAdd(&nrm_sq[row], s);
      }
    }
  }
}

// ---- pass A: bin edges into TB coarse buckets; packed entry = (src<<8)|(dst&255) ----
__global__ __launch_bounds__(1024) void k_bin(const int* __restrict__ src,
                                              const int* __restrict__ dst,
                                              int* __restrict__ cursor,
                                              int* __restrict__ binned) {
  __shared__ int hist[TB];
  __shared__ int base[TB];
  int tid = threadIdx.x;
  for (int i = tid; i < TB; i += 1024) hist[i] = 0;
  __syncthreads();
  int e0 = blockIdx.x * EPB;
  int myb[8], myrank[8], myp[8];
#pragma unroll
  for (int i = 0; i < 8; i++) {
    int e = e0 + i * 1024 + tid;
    myb[i] = -1;
    if (e < R_REL * E_EDGES) {
      int r = e / E_EDGES;
      int d = dst[e];
      int s = src[e];
      int b = r * NB + (d >> 8);
      myb[i]    = b;
      myp[i]    = (s << 8) | (d & 255);
      myrank[i] = atomicAdd(&hist[b], 1);
    }
  }
  __syncthreads();
  for (int i = tid; i < TB; i += 1024) {
    int c = hist[i];
    base[i] = c ? atomicAdd(&cursor[i], c) : 0;
  }
  __syncthreads();
#pragma unroll
  for (int i = 0; i < 8; i++) {
    if (myb[i] >= 0) {
      int pos = base[myb[i]] + myrank[i];
      if (pos < BCAP) binned[(size_t)myb[i] * BCAP + pos] = myp[i];
    }
  }
}

// ---- scan of TB bucket counts -> global bucket bases; also offsets[RN] ----
__global__ __launch_bounds__(1024) void k_bucket_scan(const int* __restrict__ cnt,
                                                      int* __restrict__ bbase,
                                                      int* __restrict__ offsets) {
  __shared__ int s[1024];
  int tid = threadIdx.x;
  int v = (tid < TB) ? cnt[tid] : 0;
  s[tid] = v;
  __syncthreads();
  for (int off = 1; off < 1024; off <<= 1) {
    int t2 = (tid >= off) ? s[tid - off] : 0;
    __syncthreads();
    s[tid] += t2;
    __syncthreads();
  }
  if (tid < TB) bbase[tid] = s[tid] - v;
  if (tid == TB - 1) offsets[RN] = s[tid];
}

// ---- pass B: per-bucket exact CSR (offsets + edge_src) ----
__global__ __launch_bounds__(256) void k_csr(const int* __restrict__ binned,
                                             const int* __restrict__ cnt_arr,
                                             const int* __restrict__ bbase,
                                             int* __restrict__ offsets,
                                             int* __restrict__ edge_src) {
  __shared__ int hist[256];
  __shared__ int excl[256];
  int b   = blockIdx.x;
  int tid = threadIdx.x;
  int cnt = cnt_arr[b]; if (cnt > BCAP) cnt = BCAP;
  int gbase = bbase[b];
  hist[tid] = 0;
  __syncthreads();
  const int* bp = binned + (size_t)b * BCAP;
  for (int i = tid; i < cnt; i += 256) atomicAdd(&hist[bp[i] & 255], 1);
  __syncthreads();
  int v = hist[tid];
  excl[tid] = v;
  __syncthreads();
  for (int off = 1; off < 256; off <<= 1) {
    int t2 = (tid >= off) ? excl[tid - off] : 0;
    __syncthreads();
    excl[tid] += t2;
    __syncthreads();
  }
  int ex = excl[tid] - v;                         // exclusive within bucket
  int r = b / NB, bloc = b % NB;
  int node = bloc * 256 + tid;
  if (node < N_NODES) offsets[r * N_NODES + node] = gbase + ex;
  hist[tid] = gbase + ex;                         // reuse as cursor
  __syncthreads();
  for (int i = tid; i < cnt; i += 256) {
    int p = bp[i];
    int pos = atomicAdd(&hist[p & 255], 1);
    edge_src[pos] = p >> 8;
  }
}

// ---- fused aggregation + final combine: one wave per dst node ----
// 16-lane group g owns relation g's edge list (1 edge/iter, 2-deep prefetch);
// lane owns 16 elements as 8 packed float2. For n>=NV the softmax combine is
// done in-register and written straight to out; h16/ma stored only for n<NV.
__global__ __launch_bounds__(256) void k_aggregate_fused(
    const unsigned short* __restrict__ hr0, const unsigned short* __restrict__ hr1,
    const unsigned short* __restrict__ hr2, const unsigned short* __restrict__ hr3,
    const unsigned short* __restrict__ ht16, const float* __restrict__ nsq,
    const int* __restrict__ offsets, const int* __restrict__ edge_src,
    unsigned short* __restrict__ h16, float* __restrict__ ma,
    float* __restrict__ out) {
  int n    = (int)((blockIdx.x * (size_t)blockDim.x + threadIdx.x) >> 6);
  int lane = threadIdx.x & 63;
  if (n >= N_NODES) return;
  int g = lane >> 4, l16 = lane & 15;

  const uint4* htp = (const uint4*)(ht16 + (size_t)n * DIM + l16 * 16);
  uint4 hta = htp[0], htb = htp[1];
  f32x2 hd2[8];
  hd2[0] = expand_bf2(hta.x); hd2[1] = expand_bf2(hta.y);
  hd2[2] = expand_bf2(hta.z); hd2[3] = expand_bf2(hta.w);
  hd2[4] = expand_bf2(htb.x); hd2[5] = expand_bf2(htb.y);
  hd2[6] = expand_bf2(htb.z); hd2[7] = expand_bf2(htb.w);
  float rd = fminf(rsqrtf(nsq[n]), 1e8f);

  const unsigned short* hr = (g == 0) ? hr0 : (g == 1) ? hr1 : (g == 2) ? hr2 : hr3;
  const float* nq = nsq + (size_t)(1 + g) * N_NODES;
  int b   = offsets[g * N_NODES + n];
  int end = offsets[g * N_NODES + n + 1];

  f32x2 acc2[8] = {};
  float asum = 0.f;

  auto loadslot = [&](int i, uint4& ua, uint4& ub, float& q) {
    if (i < end) {
      int sn = edge_src[i];
      const uint4* rp = (const uint4*)(hr + (size_t)sn * DIM + l16 * 16);
      ua = rp[0]; ub = rp[1];
      q  = nq[sn];
    }
  };
  auto consume = [&](uint4 ua, uint4 ub, float q, bool valid) {
    f32x2 hs2[8];
    hs2[0] = expand_bf2(ua.x); hs2[1] = expand_bf2(ua.y);
    hs2[2] = expand_bf2(ua.z); hs2[3] = expand_bf2(ua.w);
    hs2[4] = expand_bf2(ub.x); hs2[5] = expand_bf2(ub.y);
    hs2[6] = expand_bf2(ub.z); hs2[7] = expand_bf2(ub.w);
    f32x2 d2 = hs2[0] * hd2[0];
#pragma unroll
    for (int i = 1; i < 8; i++) d2 += hs2[i] * hd2[i];
    float num = d2.x + d2.y;
    num += __shfl_xor(num, 1);
    num += __shfl_xor(num, 2);
    num += __shfl_xor(num, 4);
    num += __shfl_xor(num, 8);
    float s = valid ? num * fminf(rsqrtf(q), 1e8f) * rd : 0.f;
    f32x2 s2 = {s, s};
#pragma unroll
    for (int i = 0; i < 8; i++) acc2[i] += hs2[i] * s2;
    asum += s;
  };

  uint4 uaA = {0,0,0,0}, ubA = {0,0,0,0}, uaB = {0,0,0,0}, ubB = {0,0,0,0};
  float qA = 1.f, qB = 1.f;
  loadslot(b,     uaA, ubA, qA);
  loadslot(b + 1, uaB, ubB, qB);
  for (int i = b; i < end; i += 2) {
    uint4 uaC = {0,0,0,0}, ubC = {0,0,0,0}, uaD = {0,0,0,0}, ubD = {0,0,0,0};
    float qC = 1.f, qD = 1.f;
    loadslot(i + 2, uaC, ubC, qC);
    loadslot(i + 3, uaD, ubD, qD);
    consume(uaA, ubA, qA, true);
    consume(uaB, ubB, qB, (i + 1) < end);
    uaA = uaC; ubA = ubC; qA = qC;
    uaB = uaD; ubB = ubD; qB = qD;
  }

  float mymean = asum / fmaxf((float)(end - b), 1.0f);

  if (n < NV_VUL) {
    us8 o1, o2;
#pragma unroll
    for (int i = 0; i < 4; i++) {
      o1[2 * i]     = f2bf_rne(acc2[i].x);
      o1[2 * i + 1] = f2bf_rne(acc2[i].y);
      o2[2 * i]     = f2bf_rne(acc2[4 + i].x);
      o2[2 * i + 1] = f2bf_rne(acc2[4 + i].y);
    }
    unsigned short* hp = h16 + ((size_t)n * R_REL + g) * DIM + l16 * 16;
    *(us8*)hp       = o1;
    *(us8*)(hp + 8) = o2;
    if (l16 == 0) ma[n * R_REL + g] = mymean;
  } else {
    // in-register softmax over the 4 groups' means
    float a1 = __shfl_xor(mymean, 16);
    float a2 = __shfl_xor(mymean, 32);
    float a3 = __shfl_xor(mymean, 48);
    float mx = fmaxf(fmaxf(mymean, a1), fmaxf(a2, a3));
    float e0 = expf(mymean - mx);
    float denom = e0 + expf(a1 - mx) + expf(a2 - mx) + expf(a3 - mx);
    float w = e0 / denom;
    f32x2 o[8];
#pragma unroll
    for (int i = 0; i < 8; i++) {
      f32x2 v = acc2[i] * (f32x2){w, w};
      v.x += __shfl_xor(v.x, 16); v.x += __shfl_xor(v.x, 32);
      v.y += __shfl_xor(v.y, 16); v.y += __shfl_xor(v.y, 32);
      o[i] = v;
    }
    if (g == 0) {
      float* op = out + (size_t)n * 256 + l16 * 16;
      float4 v0 = {o[0].x, o[0].y, o[1].x, o[1].y};
      float4 v1 = {o[2].x, o[2].y, o[3].x, o[3].y};
      float4 v2 = {o[4].x, o[4].y, o[5].x, o[5].y};
      float4 v3 = {o[6].x, o[6].y, o[7].x, o[7].y};
      *(float4*)(op + 0)  = v0;
      *(float4*)(op + 4)  = v1;
      *(float4*)(op + 8)  = v2;
      *(float4*)(op + 12) = v3;
    }
  }
}

// ------- vulnerable nodes: mask + combine from bf16 h16 (NV rows only) -------
__global__ __launch_bounds__(256) void k_vuln_combine(const unsigned short* __restrict__ h16,
                                                      const int* __restrict__ cand,
                                                      const float* __restrict__ ma,
                                                      float* __restrict__ out) {
  __shared__ float red[8][4];
  __shared__ float dist2s[8];
  __shared__ float sm[1024];
  int n   = blockIdx.x;
  int tid = threadIdx.x;                       // owns elements tid*4 .. tid*4+3
  ushort4 hb = *(const ushort4*)(h16 + (size_t)n * 1024 + tid * 4);
  float4 hv;
  hv.x = bf2f(hb.x); hv.y = bf2f(hb.y); hv.z = bf2f(hb.z); hv.w = bf2f(hb.w);
  float4 d2[8];
  int wid = tid >> 6, lane = tid & 63;
#pragma unroll
  for (int k = 0; k < 8; k++) {
    int c = cand[n * 8 + k];
    ushort4 cb = *(const ushort4*)(h16 + (size_t)c * 1024 + tid * 4);
    float4 df;
    df.x = hv.x - bf2f(cb.x); df.y = hv.y - bf2f(cb.y);
    df.z = hv.z - bf2f(cb.z); df.w = hv.w - bf2f(cb.w);
    d2[k].x = df.x * df.x; d2[k].y = df.y * df.y;
    d2[k].z = df.z * df.z; d2[k].w = df.w * df.w;
    float v = d2[k].x + d2[k].y + d2[k].z + d2[k].w;
    for (int off = 32; off; off >>= 1) v += __shfl_xor(v, off);
    if (lane == 0) red[k][wid] = v;
  }
  __syncthreads();
  if (tid < 32) {
    int k = tid >> 2, w2 = tid & 3;
    float v = red[k][w2];
    v += __shfl_xor(v, 1, 4);
    v += __shfl_xor(v, 2, 4);
    if (w2 == 0) dist2s[k] = v;
  }
  __syncthreads();
  float dk[8], mn = 1e30f;
#pragma unroll
  for (int k = 0; k < 8; k++) { dk[k] = sqrtf(dist2s[k]); mn = fminf(mn, dk[k]); }
  float se = 0.f, att[8];
#pragma unroll
  for (int k = 0; k < 8; k++) { att[k] = expf(mn - dk[k]); se += att[k]; }
  float inv = 1.f / se;
  float4 accv = {0.f, 0.f, 0.f, 0.f};
#pragma unroll
  for (int k = 0; k < 8; k++) {
    float a = att[k] * inv;
    accv.x += a * d2[k].x; accv.y += a * d2[k].y;
    accv.z += a * d2[k].z; accv.w += a * d2[k].w;
  }
  float m0 = ma[n * 4 + 0], m1 = ma[n * 4 + 1], m2 = ma[n * 4 + 2], m3 = ma[n * 4 + 3];
  float mx = fmaxf(fmaxf(m0, m1), fmaxf(m2, m3));
  float w0 = expf(m0 - mx), w1 = expf(m1 - mx), w2f = expf(m2 - mx), w3 = expf(m3 - mx);
  float winv = 1.f / (w0 + w1 + w2f + w3);
  float wr = (tid < 64) ? w0 : (tid < 128) ? w1 : (tid < 192) ? w2f : w3;
  float c = wr * winv;
  float4 o;
  o.x = c * hv.x * expf(-accv.x);
  o.y = c * hv.y * expf(-accv.y);
  o.z = c * hv.z * expf(-accv.z);
  o.w = c * hv.w * expf(-accv.w);
  *(float4*)&sm[tid * 4] = o;
  __syncthreads();
  if (tid < 256) {
    float v = sm[tid] + sm[256 + tid] + sm[512 + tid] + sm[768 + tid];
    out[(size_t)n * 256 + tid] = v;
  }
}

// ---------------- diagnostic fallback ----------------
__global__ void k_fallback(float* __restrict__ out, int out_size, float wsmb) {
  int i = blockIdx.x * blockDim.x + threadIdx.x;
  if (i < out_size) out[i] = (i == 0) ? wsmb : 0.f;
}

extern "C" void kernel_launch(void* const* d_in, const int* in_sizes, int n_in,
                              void* d_out, int out_size, void* d_ws, size_t ws_size,
                              hipStream_t stream) {
  const float* x   = (const float*)d_in[0];
  const float* We  = (const float*)d_in[1];
  const float* Wn  = (const float*)d_in[2];
  const float* bnb = (const float*)d_in[3];
  const int* src   = (const int*)d_in[4];
  const int* dst   = (const int*)d_in[5];
  const int* cand  = (const int*)d_in[6];
  float* out = (float*)d_out;

  char* ws = (char*)d_ws;
  size_t off = 0;
  auto alloc = [&](size_t bytes) -> void* {
    void* p = ws + off;
    off += (bytes + 255) & ~(size_t)255;
    return p;
  };
  unsigned short* ht16        = (unsigned short*)alloc((size_t)N_NODES * DIM * 2);          // 25.6 MB
  unsigned short* h16         = (unsigned short*)alloc((size_t)NV_VUL * R_REL * DIM * 2);   // 20.5 MB (vuln rows only)
  float*          ma          = (float*)alloc((size_t)NV_VUL * R_REL * 4);
  float*          nsq         = (float*)alloc((size_t)5 * N_NODES * 4);                     // [0]=ht, [1+r]=hr
  int*            bucket_cnt  = (int*)alloc((size_t)TB * 4);
  int*            bucket_base = (int*)alloc((size_t)TB * 4);
  int*            offsets     = (int*)alloc((size_t)(RN + 1) * 4);
  int*            edge_src    = (int*)alloc((size_t)R_REL * E_EDGES * 4);                   // 8 MB
  short*          Bthi        = (short*)alloc((size_t)5 * 65536 * 2);                       // 0.66 MB
  unsigned short* hr0         = (unsigned short*)alloc((size_t)N_NODES * DIM * 2);          // 25.6 MB
  unsigned short* hr1         = (unsigned short*)alloc((size_t)N_NODES * DIM * 2);          // 25.6 MB
  unsigned short* hr2         = (unsigned short*)alloc((size_t)N_NODES * DIM * 2);          // 25.6 MB
  unsigned short* hr3         = (unsigned short*)alloc((size_t)N_NODES * DIM * 2);          // 25.6 MB
  size_t required = off;
  (void)in_sizes; (void)n_in;

  if (ws_size < required) {
    k_fallback<<<(out_size + 255) / 256, 256, 0, stream>>>(out, out_size,
                                                           (float)(ws_size >> 20));
    return;
  }

  int* binned = (int*)h16;       // 16.06 MB bin staging aliases h16 (dead before aggregate)

  hipMemsetAsync(bucket_cnt, 0, (size_t)TB * 4, stream);
  hipMemsetAsync(nsq, 0, (size_t)5 * N_NODES * 4, stream);

  k_convert_w<<<dim3(4, 4, 5), 256, 0, stream>>>(Wn, We, Bthi);

  dim3 gemm_grid((N_NODES + GBM - 1) / GBM, DIM / GBN);

  // ht16 = bf16(x @ Wn + bn) (1-pass MFMA), fused sumsq
  k_gemm_bf16<<<gemm_grid, 256, 0, stream>>>(x, Bthi, bnb, ht16, nsq, N_NODES);

  // binned CSR build: bin -> bucket scan -> per-bucket CSR
  k_bin<<<(R_REL * E_EDGES + EPB - 1) / EPB, 1024, 0, stream>>>(src, dst, bucket_cnt, binned);
  k_bucket_scan<<<1, 1024, 0, stream>>>(bucket_cnt, bucket_base, offsets);
  k_csr<<<TB, 256, 0, stream>>>(binned, bucket_cnt, bucket_base, offsets, edge_src);

  // hr16[r] = bf16(x @ We[r]) (1-pass MFMA) + fused sumsq
  unsigned short* hrs[4] = {hr0, hr1, hr2, hr3};
  for (int r = 0; r < R_REL; r++)
    k_gemm_bf16<<<gemm_grid, 256, 0, stream>>>(x, Bthi + (size_t)(1 + r) * 65536, nullptr,
                                               hrs[r], nsq + (size_t)(1 + r) * N_NODES, N_NODES);

  // fused aggregation + combine (writes h16/ma for n<NV, out rows [NV,N) directly)
  k_aggregate_fused<<<(N_NODES * 64 + 255) / 256, 256, 0, stream>>>(
      hr0, hr1, hr2, hr3, ht16, nsq, offsets, edge_src, h16, ma, out);

  // vulnerable nodes: mask + combine (reads h16, writes out rows [0, NV))
  k_vuln_combine<<<NV_VUL, 256, 0, stream>>>(h16, cand, ma, out);
}